// Round 1
// baseline (1058.257 us; speedup 1.0000x reference)
//
#include <hip/hip_runtime.h>

#define N_NODES 100000
#define N_EDGES 1600000
#define F_INPUT 4
#define HDIM 64
#define G_GRAPHS 1000
#define C_CLS 3

// ---------------- embedding: h = x @ w_emb + b_emb ----------------
__global__ void k_emb(const float* __restrict__ x, const float* __restrict__ w,
                      const float* __restrict__ b, float* __restrict__ h) {
    int t = blockIdx.x * blockDim.x + threadIdx.x;
    if (t >= N_NODES * HDIM) return;
    int n = t >> 6, f = t & 63;
    const float* xr = x + n * F_INPUT;
    float acc = b[f];
#pragma unroll
    for (int k = 0; k < F_INPUT; ++k) acc += xr[k] * w[k * HDIM + f];
    h[t] = acc;
}

// ---------------- wsum[i] = sum of edge_attr over incoming edges ----------------
__global__ void k_wsum(const int* __restrict__ dst, const float* __restrict__ attr,
                       float* __restrict__ wsum) {
    int e = blockIdx.x * blockDim.x + threadIdx.x;
    if (e >= N_EDGES) return;
    atomicAdd(&wsum[dst[e]], attr[e]);
}

// ---------------- fused 3-GEMM: a = hW1+b1 ; d = hW3+b3 - (hW2)*wsum ----------------
__global__ __launch_bounds__(256) void k_gemm3(
    const float* __restrict__ h,
    const float* __restrict__ W1, const float* __restrict__ b1,
    const float* __restrict__ W2,
    const float* __restrict__ W3, const float* __restrict__ b3,
    const float* __restrict__ wsum,
    float* __restrict__ a_out, float* __restrict__ d_out_) {
    __shared__ float sW[3 * HDIM * HDIM];  // 48 KB
    int tid = threadIdx.x;
    for (int i = tid; i < HDIM * HDIM; i += 256) {
        sW[i] = W1[i];
        sW[HDIM * HDIM + i] = W2[i];
        sW[2 * HDIM * HDIM + i] = W3[i];
    }
    __syncthreads();

    int f0 = (tid & 15) * 4;
    int n0 = blockIdx.x * 64 + (tid >> 4) * 4;

    float acc[3][4][4];
#pragma unroll
    for (int m = 0; m < 3; ++m)
#pragma unroll
        for (int j = 0; j < 4; ++j)
#pragma unroll
            for (int c = 0; c < 4; ++c) acc[m][j][c] = 0.f;

    for (int k4 = 0; k4 < HDIM; k4 += 4) {
        float hr[4][4];
#pragma unroll
        for (int j = 0; j < 4; ++j) {
            int n = n0 + j;
            if (n < N_NODES) {
                float4 v = *(const float4*)(h + n * HDIM + k4);
                hr[j][0] = v.x; hr[j][1] = v.y; hr[j][2] = v.z; hr[j][3] = v.w;
            } else {
                hr[j][0] = hr[j][1] = hr[j][2] = hr[j][3] = 0.f;
            }
        }
#pragma unroll
        for (int kk = 0; kk < 4; ++kk) {
            int k = k4 + kk;
            float4 w1 = *(const float4*)&sW[k * HDIM + f0];
            float4 w2 = *(const float4*)&sW[HDIM * HDIM + k * HDIM + f0];
            float4 w3 = *(const float4*)&sW[2 * HDIM * HDIM + k * HDIM + f0];
#pragma unroll
            for (int j = 0; j < 4; ++j) {
                float hv = hr[j][kk];
                acc[0][j][0] += hv * w1.x; acc[0][j][1] += hv * w1.y;
                acc[0][j][2] += hv * w1.z; acc[0][j][3] += hv * w1.w;
                acc[1][j][0] += hv * w2.x; acc[1][j][1] += hv * w2.y;
                acc[1][j][2] += hv * w2.z; acc[1][j][3] += hv * w2.w;
                acc[2][j][0] += hv * w3.x; acc[2][j][1] += hv * w3.y;
                acc[2][j][2] += hv * w3.z; acc[2][j][3] += hv * w3.w;
            }
        }
    }

#pragma unroll
    for (int j = 0; j < 4; ++j) {
        int n = n0 + j;
        if (n >= N_NODES) continue;
        float ws = wsum[n];
        float4 av, dv;
        av.x = acc[0][j][0] + b1[f0 + 0];
        av.y = acc[0][j][1] + b1[f0 + 1];
        av.z = acc[0][j][2] + b1[f0 + 2];
        av.w = acc[0][j][3] + b1[f0 + 3];
        dv.x = acc[2][j][0] + b3[f0 + 0] - acc[1][j][0] * ws;
        dv.y = acc[2][j][1] + b3[f0 + 1] - acc[1][j][1] * ws;
        dv.z = acc[2][j][2] + b3[f0 + 2] - acc[1][j][2] * ws;
        dv.w = acc[2][j][3] + b3[f0 + 3] - acc[1][j][3] * ws;
        *(float4*)(a_out + n * HDIM + f0) = av;
        *(float4*)(d_out_ + n * HDIM + f0) = dv;
    }
}

// ---------------- edge scatter: agg[dst][f] += a[src][f] * w[e] ----------------
__global__ void k_scatter(const int* __restrict__ src, const int* __restrict__ dstArr,
                          const float* __restrict__ attr, const float* __restrict__ a,
                          float* __restrict__ agg) {
    int t = blockIdx.x * blockDim.x + threadIdx.x;
    int e = t >> 6;
    if (e >= N_EDGES) return;
    int f = t & 63;
    int s = src[e], d = dstArr[e];
    float w = attr[e];
    atomicAdd(&agg[d * HDIM + f], a[s * HDIM + f] * w);
}

// ---------------- h = relu(agg + d) ----------------
__global__ void k_relu(const float* __restrict__ agg, const float* __restrict__ dbuf,
                       float* __restrict__ h) {
    int t = blockIdx.x * blockDim.x + threadIdx.x;
    if (t >= N_NODES * HDIM) return;
    h[t] = fmaxf(agg[t] + dbuf[t], 0.f);
}

// ---------------- pooling: graph sums + counts ----------------
__global__ void k_pool(const float* __restrict__ h, const int* __restrict__ batch,
                       float* __restrict__ gsum, float* __restrict__ gcnt) {
    int t = blockIdx.x * blockDim.x + threadIdx.x;
    if (t >= N_NODES * HDIM) return;
    int n = t >> 6, f = t & 63;
    int b = batch[n];
    atomicAdd(&gsum[b * HDIM + f], h[t]);
    if (f == 0) atomicAdd(&gcnt[b], 1.0f);
}

// ---------------- head: out = relu(gx@W1+b1)@W2+b2 ----------------
__global__ void k_head(const float* __restrict__ gsum, const float* __restrict__ gcnt,
                       const float* __restrict__ W1, const float* __restrict__ b1,
                       const float* __restrict__ W2, const float* __restrict__ b2,
                       float* __restrict__ out) {
    int g = blockIdx.x;
    __shared__ float sx[HDIM];
    __shared__ float sy[2 * HDIM];
    int tid = threadIdx.x;
    float cnt = fmaxf(gcnt[g], 1.0f);
    if (tid < HDIM) sx[tid] = gsum[g * HDIM + tid] / cnt;
    __syncthreads();
    float acc = b1[tid];
    for (int k = 0; k < HDIM; ++k) acc += sx[k] * W1[k * 2 * HDIM + tid];
    sy[tid] = fmaxf(acc, 0.f);
    __syncthreads();
    if (tid < C_CLS) {
        float o = b2[tid];
        for (int k = 0; k < 2 * HDIM; ++k) o += sy[k] * W2[k * C_CLS + tid];
        out[g * C_CLS + tid] = o;
    }
}

extern "C" void kernel_launch(void* const* d_in, const int* in_sizes, int n_in,
                              void* d_out, int out_size, void* d_ws, size_t ws_size,
                              hipStream_t stream) {
    const float* x        = (const float*)d_in[0];
    const int*   ei       = (const int*)d_in[1];
    const float* eattr    = (const float*)d_in[2];
    const int*   batch    = (const int*)d_in[3];
    const float* w_emb    = (const float*)d_in[4];
    const float* b_emb    = (const float*)d_in[5];
    const float* lin1_w   = (const float*)d_in[6];
    const float* lin1_b   = (const float*)d_in[7];
    const float* lin2_w   = (const float*)d_in[8];
    const float* lin3_w   = (const float*)d_in[9];
    const float* lin3_b   = (const float*)d_in[10];
    const float* mlp_w1   = (const float*)d_in[11];
    const float* mlp_b1   = (const float*)d_in[12];
    const float* mlp_w2   = (const float*)d_in[13];
    const float* mlp_b2   = (const float*)d_in[14];
    float* out = (float*)d_out;

    const int* src = ei;
    const int* dst = ei + N_EDGES;

    float* ws = (float*)d_ws;
    const size_t NH = (size_t)N_NODES * HDIM;
    float* h    = ws;
    float* a    = h + NH;
    float* dbuf = a + NH;
    float* agg  = dbuf + NH;
    float* wsum = agg + NH;
    float* gsum = wsum + N_NODES;
    float* gcnt = gsum + (size_t)G_GRAPHS * HDIM;

    // zero accumulators that are accumulated via atomics
    hipMemsetAsync(wsum, 0, N_NODES * sizeof(float), stream);
    hipMemsetAsync(gsum, 0, (G_GRAPHS * HDIM + G_GRAPHS) * sizeof(float), stream);

    int nh_blocks = (N_NODES * HDIM + 255) / 256;
    k_emb<<<nh_blocks, 256, 0, stream>>>(x, w_emb, b_emb, h);
    k_wsum<<<(N_EDGES + 255) / 256, 256, 0, stream>>>(dst, eattr, wsum);

    int gemm_blocks = (N_NODES + 63) / 64;
    int scat_blocks = (N_EDGES * 64) / 256;

    for (int l = 0; l < 2; ++l) {
        const float* W1 = lin1_w + l * HDIM * HDIM;
        const float* B1 = lin1_b + l * HDIM;
        const float* W2 = lin2_w + l * HDIM * HDIM;
        const float* W3 = lin3_w + l * HDIM * HDIM;
        const float* B3 = lin3_b + l * HDIM;
        k_gemm3<<<gemm_blocks, 256, 0, stream>>>(h, W1, B1, W2, W3, B3, wsum, a, dbuf);
        hipMemsetAsync(agg, 0, NH * sizeof(float), stream);
        k_scatter<<<scat_blocks, 256, 0, stream>>>(src, dst, eattr, a, agg);
        k_relu<<<nh_blocks, 256, 0, stream>>>(agg, dbuf, h);
    }

    k_pool<<<nh_blocks, 256, 0, stream>>>(h, batch, gsum, gcnt);
    k_head<<<G_GRAPHS, 2 * HDIM, 0, stream>>>(gsum, gcnt, mlp_w1, mlp_b1, mlp_w2, mlp_b2, out);
}

// Round 2
// 582.591 us; speedup vs baseline: 1.8165x; 1.8165x over previous
//
#include <hip/hip_runtime.h>

#define N_NODES 100000
#define N_EDGES 1600000
#define F_INPUT 4
#define HDIM 64
#define G_GRAPHS 1000
#define C_CLS 3

// ---------------- embedding: h = x @ w_emb + b_emb ----------------
__global__ void k_emb(const float* __restrict__ x, const float* __restrict__ w,
                      const float* __restrict__ b, float* __restrict__ h) {
    int t = blockIdx.x * blockDim.x + threadIdx.x;
    if (t >= N_NODES * HDIM) return;
    int n = t >> 6, f = t & 63;
    const float* xr = x + n * F_INPUT;
    float acc = b[f];
#pragma unroll
    for (int k = 0; k < F_INPUT; ++k) acc += xr[k] * w[k * HDIM + f];
    h[t] = acc;
}

// ---------------- CSR build: degree count ----------------
__global__ void k_count(const int* __restrict__ dst, int* __restrict__ deg) {
    int e = blockIdx.x * blockDim.x + threadIdx.x;
    if (e >= N_EDGES) return;
    atomicAdd(&deg[dst[e]], 1);
}

// ---------------- CSR build: block-level exclusive scan ----------------
// 1024 elements per block, 256 threads x 4
__global__ __launch_bounds__(256) void k_scan1(const int* __restrict__ deg,
                                               int* __restrict__ off,
                                               int* __restrict__ bsum) {
    __shared__ int s[256];
    int t = threadIdx.x;
    int i0 = blockIdx.x * 1024 + t * 4;
    int v0 = (i0 + 0 < N_NODES) ? deg[i0 + 0] : 0;
    int v1 = (i0 + 1 < N_NODES) ? deg[i0 + 1] : 0;
    int v2 = (i0 + 2 < N_NODES) ? deg[i0 + 2] : 0;
    int v3 = (i0 + 3 < N_NODES) ? deg[i0 + 3] : 0;
    int tot = v0 + v1 + v2 + v3;
    s[t] = tot;
    __syncthreads();
    for (int d = 1; d < 256; d <<= 1) {
        int x = (t >= d) ? s[t - d] : 0;
        __syncthreads();
        s[t] += x;
        __syncthreads();
    }
    int e0 = s[t] - tot;  // exclusive base for this thread
    if (i0 + 0 < N_NODES) off[i0 + 0] = e0;
    if (i0 + 1 < N_NODES) off[i0 + 1] = e0 + v0;
    if (i0 + 2 < N_NODES) off[i0 + 2] = e0 + v0 + v1;
    if (i0 + 3 < N_NODES) off[i0 + 3] = e0 + v0 + v1 + v2;
    if (t == 255) bsum[blockIdx.x] = s[255];
}

#define SCAN_NB 98  // ceil(100000/1024)

__global__ __launch_bounds__(128) void k_scan2(int* __restrict__ bsum) {
    __shared__ int s[128];
    int t = threadIdx.x;
    int v = (t < SCAN_NB) ? bsum[t] : 0;
    s[t] = v;
    __syncthreads();
    for (int d = 1; d < 128; d <<= 1) {
        int x = (t >= d) ? s[t - d] : 0;
        __syncthreads();
        s[t] += x;
        __syncthreads();
    }
    if (t < SCAN_NB) bsum[t] = s[t] - v;  // exclusive
}

__global__ __launch_bounds__(256) void k_scan3(int* __restrict__ off,
                                               const int* __restrict__ bsum) {
    int t = threadIdx.x;
    int i0 = blockIdx.x * 1024 + t * 4;
    int add = bsum[blockIdx.x];
#pragma unroll
    for (int k = 0; k < 4; ++k)
        if (i0 + k < N_NODES) off[i0 + k] += add;
    if (blockIdx.x == 0 && t == 0) off[N_NODES] = N_EDGES;
}

// ---------------- CSR build: fill sorted edge arrays ----------------
__global__ void k_fill(const int* __restrict__ src, const int* __restrict__ dst,
                       const float* __restrict__ attr, const int* __restrict__ off,
                       int* __restrict__ cursor, int* __restrict__ esrc,
                       float* __restrict__ eat) {
    int e = blockIdx.x * blockDim.x + threadIdx.x;
    if (e >= N_EDGES) return;
    int d = dst[e];
    int r = atomicAdd(&cursor[d], 1);
    int p = off[d] + r;
    esrc[p] = src[e];
    eat[p] = attr[e];
}

// ---------------- wsum[i] via CSR (deterministic) ----------------
__global__ void k_wsum(const int* __restrict__ off, const float* __restrict__ eat,
                       float* __restrict__ wsum) {
    int n = blockIdx.x * blockDim.x + threadIdx.x;
    if (n >= N_NODES) return;
    int lo = off[n], hi = off[n + 1];
    float s = 0.f;
    for (int j = lo; j < hi; ++j) s += eat[j];
    wsum[n] = s;
}

// ---------------- fused 3-GEMM: a = hW1+b1 ; d = hW3+b3 - (hW2)*wsum ----------------
__global__ __launch_bounds__(256) void k_gemm3(
    const float* __restrict__ h,
    const float* __restrict__ W1, const float* __restrict__ b1,
    const float* __restrict__ W2,
    const float* __restrict__ W3, const float* __restrict__ b3,
    const float* __restrict__ wsum,
    float* __restrict__ a_out, float* __restrict__ d_out_) {
    __shared__ float sW[3 * HDIM * HDIM];  // 48 KB
    int tid = threadIdx.x;
    for (int i = tid; i < HDIM * HDIM; i += 256) {
        sW[i] = W1[i];
        sW[HDIM * HDIM + i] = W2[i];
        sW[2 * HDIM * HDIM + i] = W3[i];
    }
    __syncthreads();

    int f0 = (tid & 15) * 4;
    int n0 = blockIdx.x * 64 + (tid >> 4) * 4;

    float acc[3][4][4];
#pragma unroll
    for (int m = 0; m < 3; ++m)
#pragma unroll
        for (int j = 0; j < 4; ++j)
#pragma unroll
            for (int c = 0; c < 4; ++c) acc[m][j][c] = 0.f;

    for (int k4 = 0; k4 < HDIM; k4 += 4) {
        float hr[4][4];
#pragma unroll
        for (int j = 0; j < 4; ++j) {
            int n = n0 + j;
            if (n < N_NODES) {
                float4 v = *(const float4*)(h + n * HDIM + k4);
                hr[j][0] = v.x; hr[j][1] = v.y; hr[j][2] = v.z; hr[j][3] = v.w;
            } else {
                hr[j][0] = hr[j][1] = hr[j][2] = hr[j][3] = 0.f;
            }
        }
#pragma unroll
        for (int kk = 0; kk < 4; ++kk) {
            int k = k4 + kk;
            float4 w1 = *(const float4*)&sW[k * HDIM + f0];
            float4 w2 = *(const float4*)&sW[HDIM * HDIM + k * HDIM + f0];
            float4 w3 = *(const float4*)&sW[2 * HDIM * HDIM + k * HDIM + f0];
#pragma unroll
            for (int j = 0; j < 4; ++j) {
                float hv = hr[j][kk];
                acc[0][j][0] += hv * w1.x; acc[0][j][1] += hv * w1.y;
                acc[0][j][2] += hv * w1.z; acc[0][j][3] += hv * w1.w;
                acc[1][j][0] += hv * w2.x; acc[1][j][1] += hv * w2.y;
                acc[1][j][2] += hv * w2.z; acc[1][j][3] += hv * w2.w;
                acc[2][j][0] += hv * w3.x; acc[2][j][1] += hv * w3.y;
                acc[2][j][2] += hv * w3.z; acc[2][j][3] += hv * w3.w;
            }
        }
    }

#pragma unroll
    for (int j = 0; j < 4; ++j) {
        int n = n0 + j;
        if (n >= N_NODES) continue;
        float ws = wsum[n];
        float4 av, dv;
        av.x = acc[0][j][0] + b1[f0 + 0];
        av.y = acc[0][j][1] + b1[f0 + 1];
        av.z = acc[0][j][2] + b1[f0 + 2];
        av.w = acc[0][j][3] + b1[f0 + 3];
        dv.x = acc[2][j][0] + b3[f0 + 0] - acc[1][j][0] * ws;
        dv.y = acc[2][j][1] + b3[f0 + 1] - acc[1][j][1] * ws;
        dv.z = acc[2][j][2] + b3[f0 + 2] - acc[1][j][2] * ws;
        dv.w = acc[2][j][3] + b3[f0 + 3] - acc[1][j][3] * ws;
        *(float4*)(a_out + n * HDIM + f0) = av;
        *(float4*)(d_out_ + n * HDIM + f0) = dv;
    }
}

// ---------------- CSR aggregate + relu fuse: h = relu(sum_j a[src_j]*w_j + d) ----------------
__global__ __launch_bounds__(256) void k_agg(const int* __restrict__ esrc,
                                             const float* __restrict__ eat,
                                             const int* __restrict__ off,
                                             const float* __restrict__ a,
                                             const float* __restrict__ dbuf,
                                             float* __restrict__ h) {
    int wid = threadIdx.x >> 6;
    int lane = threadIdx.x & 63;
    int n = blockIdx.x * 4 + wid;
    if (n >= N_NODES) return;
    int lo = off[n], hi = off[n + 1];
    float acc = 0.f;
    for (int j0 = lo; j0 < hi; j0 += 64) {
        int idx = 0;
        float w = 0.f;
        if (j0 + lane < hi) {
            idx = esrc[j0 + lane];
            w = eat[j0 + lane];
        }
        int cnt = min(64, hi - j0);
        for (int k = 0; k < cnt; ++k) {
            int s = __shfl(idx, k);
            float ww = __shfl(w, k);
            acc += a[(size_t)s * HDIM + lane] * ww;
        }
    }
    size_t o = (size_t)n * HDIM + lane;
    h[o] = fmaxf(acc + dbuf[o], 0.f);
}

// ---------------- graph boundaries from sorted batch ----------------
__global__ void k_bounds(const int* __restrict__ batch, int* __restrict__ goff) {
    int n = blockIdx.x * blockDim.x + threadIdx.x;
    if (n >= N_NODES) return;
    int b = batch[n];
    int bp = (n == 0) ? -1 : batch[n - 1];
    for (int g = bp + 1; g <= b; ++g) goff[g] = n;
    if (n == N_NODES - 1) {
        for (int g = b + 1; g <= G_GRAPHS; ++g) goff[g] = N_NODES;
    }
}

// ---------------- mean pool: one wave per graph ----------------
__global__ __launch_bounds__(64) void k_pool(const float* __restrict__ h,
                                             const int* __restrict__ goff,
                                             float* __restrict__ gx) {
    int g = blockIdx.x;
    int lane = threadIdx.x;
    int lo = goff[g], hi = goff[g + 1];
    float acc = 0.f;
    for (int n = lo; n < hi; ++n) acc += h[(size_t)n * HDIM + lane];
    float cnt = (float)(hi - lo);
    gx[g * HDIM + lane] = acc / fmaxf(cnt, 1.f);
}

// ---------------- head: out = relu(gx@W1+b1)@W2+b2 ----------------
__global__ __launch_bounds__(128) void k_head(const float* __restrict__ gx,
                                              const float* __restrict__ W1,
                                              const float* __restrict__ b1,
                                              const float* __restrict__ W2,
                                              const float* __restrict__ b2,
                                              float* __restrict__ out) {
    int g = blockIdx.x;
    __shared__ float sx[HDIM];
    __shared__ float sy[2 * HDIM];
    int tid = threadIdx.x;
    if (tid < HDIM) sx[tid] = gx[g * HDIM + tid];
    __syncthreads();
    float acc = b1[tid];
    for (int k = 0; k < HDIM; ++k) acc += sx[k] * W1[k * 2 * HDIM + tid];
    sy[tid] = fmaxf(acc, 0.f);
    __syncthreads();
    if (tid < C_CLS) {
        float o = b2[tid];
        for (int k = 0; k < 2 * HDIM; ++k) o += sy[k] * W2[k * C_CLS + tid];
        out[g * C_CLS + tid] = o;
    }
}

extern "C" void kernel_launch(void* const* d_in, const int* in_sizes, int n_in,
                              void* d_out, int out_size, void* d_ws, size_t ws_size,
                              hipStream_t stream) {
    const float* x      = (const float*)d_in[0];
    const int*   ei     = (const int*)d_in[1];
    const float* eattr  = (const float*)d_in[2];
    const int*   batch  = (const int*)d_in[3];
    const float* w_emb  = (const float*)d_in[4];
    const float* b_emb  = (const float*)d_in[5];
    const float* lin1_w = (const float*)d_in[6];
    const float* lin1_b = (const float*)d_in[7];
    const float* lin2_w = (const float*)d_in[8];
    const float* lin3_w = (const float*)d_in[9];
    const float* lin3_b = (const float*)d_in[10];
    const float* mlp_w1 = (const float*)d_in[11];
    const float* mlp_b1 = (const float*)d_in[12];
    const float* mlp_w2 = (const float*)d_in[13];
    const float* mlp_b2 = (const float*)d_in[14];
    float* out = (float*)d_out;

    const int* src = ei;
    const int* dst = ei + N_EDGES;

    const size_t NH = (size_t)N_NODES * HDIM;
    float* fws = (float*)d_ws;
    float* h    = fws;                 // NH
    float* a    = h + NH;              // NH
    float* dbuf = a + NH;              // NH
    float* eat  = dbuf + NH;           // E
    float* wsum = eat + N_EDGES;       // N
    float* gx   = wsum + N_NODES;      // G*H
    int* iws    = (int*)(gx + (size_t)G_GRAPHS * HDIM);
    int* esrc   = iws;                 // E
    int* off    = esrc + N_EDGES;      // N+1
    int* deg    = off + N_NODES + 1;   // N   (zeroed)
    int* cursor = deg + N_NODES;       // N   (zeroed)
    int* bsum   = cursor + N_NODES;    // SCAN_NB
    int* goff   = bsum + SCAN_NB;      // G+1

    // zero deg + cursor (adjacent)
    hipMemsetAsync(deg, 0, 2 * N_NODES * sizeof(int), stream);

    int nh_blocks = (N_NODES * HDIM + 255) / 256;
    int e_blocks = (N_EDGES + 255) / 256;
    int n_blocks = (N_NODES + 255) / 256;

    k_emb<<<nh_blocks, 256, 0, stream>>>(x, w_emb, b_emb, h);
    k_count<<<e_blocks, 256, 0, stream>>>(dst, deg);
    k_scan1<<<SCAN_NB, 256, 0, stream>>>(deg, off, bsum);
    k_scan2<<<1, 128, 0, stream>>>(bsum);
    k_scan3<<<SCAN_NB, 256, 0, stream>>>(off, bsum);
    k_fill<<<e_blocks, 256, 0, stream>>>(src, dst, eattr, off, cursor, esrc, eat);
    k_wsum<<<n_blocks, 256, 0, stream>>>(off, eat, wsum);
    k_bounds<<<n_blocks, 256, 0, stream>>>(batch, goff);

    int gemm_blocks = (N_NODES + 63) / 64;
    int agg_blocks = (N_NODES + 3) / 4;

    for (int l = 0; l < 2; ++l) {
        const float* W1 = lin1_w + l * HDIM * HDIM;
        const float* B1 = lin1_b + l * HDIM;
        const float* W2 = lin2_w + l * HDIM * HDIM;
        const float* W3 = lin3_w + l * HDIM * HDIM;
        const float* B3 = lin3_b + l * HDIM;
        k_gemm3<<<gemm_blocks, 256, 0, stream>>>(h, W1, B1, W2, W3, B3, wsum, a, dbuf);
        k_agg<<<agg_blocks, 256, 0, stream>>>(esrc, eat, off, a, dbuf, h);
    }

    k_pool<<<G_GRAPHS, 64, 0, stream>>>(h, goff, gx);
    k_head<<<G_GRAPHS, 128, 0, stream>>>(gx, mlp_w1, mlp_b1, mlp_w2, mlp_b2, out);
}

// Round 3
// 453.078 us; speedup vs baseline: 2.3357x; 1.2859x over previous
//
#include <hip/hip_runtime.h>

#define N_NODES 100000
#define N_EDGES 1600000
#define F_INPUT 4
#define HDIM 64
#define G_GRAPHS 1000
#define C_CLS 3

#define NPB 512          // nodes per bucket (power of 2)
#define BSHIFT 9
#define NB 196           // ceil(N_NODES / NPB)
#define CBLK 391         // ceil(N_EDGES / 4096)

// ---------------- embedding: h = x @ w_emb + b_emb ----------------
__global__ void k_emb(const float* __restrict__ x, const float* __restrict__ w,
                      const float* __restrict__ b, float* __restrict__ h) {
    int t = blockIdx.x * blockDim.x + threadIdx.x;
    if (t >= N_NODES * HDIM) return;
    int n = t >> 6, f = t & 63;
    const float* xr = x + n * F_INPUT;
    float acc = b[f];
#pragma unroll
    for (int k = 0; k < F_INPUT; ++k) acc += xr[k] * w[k * HDIM + f];
    h[t] = acc;
}

// ---------------- bucket histogram (LDS-aggregated) ----------------
__global__ __launch_bounds__(256) void k_hist(const int* __restrict__ dst,
                                              int* __restrict__ bcnt) {
    __shared__ int s[NB];
    for (int i = threadIdx.x; i < NB; i += 256) s[i] = 0;
    __syncthreads();
    for (int e = blockIdx.x * 256 + threadIdx.x; e < N_EDGES; e += 512 * 256)
        atomicAdd(&s[dst[e] >> BSHIFT], 1);
    __syncthreads();
    for (int i = threadIdx.x; i < NB; i += 256)
        if (s[i]) atomicAdd(&bcnt[i], s[i]);
}

// ---------------- bucket offsets: scan of 196 values ----------------
__global__ __launch_bounds__(256) void k_boff(const int* __restrict__ bcnt,
                                              int* __restrict__ boff,
                                              int* __restrict__ bcur) {
    __shared__ int s[256];
    int t = threadIdx.x;
    int v = (t < NB) ? bcnt[t] : 0;
    s[t] = v;
    __syncthreads();
    for (int d = 1; d < 256; d <<= 1) {
        int x = (t >= d) ? s[t - d] : 0;
        __syncthreads();
        s[t] += x;
        __syncthreads();
    }
    int ex = s[t] - v;
    if (t < NB) { boff[t] = ex; bcur[t] = ex; }
    if (t == 0) boff[NB] = N_EDGES;
}

// ---------------- scatter edges into buckets (packed 8B records) ----------------
// record: x = src | (dloc << 17) ; y = bits of w
__global__ __launch_bounds__(1024) void k_bucket(const int* __restrict__ src,
                                                 const int* __restrict__ dst,
                                                 const float* __restrict__ attr,
                                                 int* __restrict__ bcur,
                                                 int2* __restrict__ bbuf) {
    __shared__ int cnt[NB];
    __shared__ int base[NB];
    for (int i = threadIdx.x; i < NB; i += 1024) cnt[i] = 0;
    __syncthreads();
    int e0 = blockIdx.x * 4096;
    int myb[4], myrank[4];
    int2 mypack[4];
#pragma unroll
    for (int k = 0; k < 4; ++k) {
        int e = e0 + k * 1024 + threadIdx.x;
        if (e < N_EDGES) {
            int d = dst[e];
            int b = d >> BSHIFT;
            myb[k] = b;
            myrank[k] = atomicAdd(&cnt[b], 1);
            mypack[k].x = src[e] | ((d & (NPB - 1)) << 17);
            mypack[k].y = __float_as_int(attr[e]);
        } else
            myb[k] = -1;
    }
    __syncthreads();
    for (int i = threadIdx.x; i < NB; i += 1024)
        base[i] = cnt[i] ? atomicAdd(&bcur[i], cnt[i]) : 0;
    __syncthreads();
#pragma unroll
    for (int k = 0; k < 4; ++k)
        if (myb[k] >= 0) bbuf[base[myb[k]] + myrank[k]] = mypack[k];
}

// ---------------- per-bucket CSR finalize: off, wsum, sorted edge2 ----------------
__global__ __launch_bounds__(256) void k_csr(const int2* __restrict__ bbuf,
                                             const int* __restrict__ boff,
                                             int* __restrict__ off,
                                             float* __restrict__ wsum,
                                             int2* __restrict__ edge2) {
    __shared__ int deg[NPB];
    __shared__ float wsm[NPB];
    __shared__ int loff[NPB];
    __shared__ int sct[256];
    int b = blockIdx.x;
    int lo = boff[b], hi = boff[b + 1];
    int t = threadIdx.x;
    for (int i = t; i < NPB; i += 256) { deg[i] = 0; wsm[i] = 0.f; }
    __syncthreads();
    for (int j = lo + t; j < hi; j += 256) {
        int2 p = bbuf[j];
        int dloc = (p.x >> 17) & (NPB - 1);
        atomicAdd(&deg[dloc], 1);
        atomicAdd(&wsm[dloc], __int_as_float(p.y));
    }
    __syncthreads();
    // exclusive scan of deg[512] (2 per thread)
    int v0 = deg[2 * t], v1 = deg[2 * t + 1];
    int tot = v0 + v1;
    sct[t] = tot;
    __syncthreads();
    for (int d = 1; d < 256; d <<= 1) {
        int x = (t >= d) ? sct[t - d] : 0;
        __syncthreads();
        sct[t] += x;
        __syncthreads();
    }
    int ex = sct[t] - tot;
    loff[2 * t] = ex;
    loff[2 * t + 1] = ex + v0;
    __syncthreads();
    int nbase = b * NPB;
    for (int i = t; i < NPB; i += 256) {
        int n = nbase + i;
        if (n < N_NODES) { off[n] = lo + loff[i]; wsum[n] = wsm[i]; }
    }
    if (b == NB - 1 && t == 0) off[N_NODES] = N_EDGES;
    // reuse deg as cursor
    for (int i = t; i < NPB; i += 256) deg[i] = 0;
    __syncthreads();
    for (int j = lo + t; j < hi; j += 256) {
        int2 p = bbuf[j];
        int dloc = (p.x >> 17) & (NPB - 1);
        int r = atomicAdd(&deg[dloc], 1);
        edge2[lo + loff[dloc] + r] = make_int2(p.x & 0x1FFFF, p.y);
    }
}

// ---------------- fused 3-GEMM: a = hW1+b1 ; d = hW3+b3 - (hW2)*wsum ----------------
__global__ __launch_bounds__(256) void k_gemm3(
    const float* __restrict__ h,
    const float* __restrict__ W1, const float* __restrict__ b1,
    const float* __restrict__ W2,
    const float* __restrict__ W3, const float* __restrict__ b3,
    const float* __restrict__ wsum,
    float* __restrict__ a_out, float* __restrict__ d_out_) {
    __shared__ float sW[3 * HDIM * HDIM];  // 48 KB
    int tid = threadIdx.x;
    for (int i = tid; i < HDIM * HDIM; i += 256) {
        sW[i] = W1[i];
        sW[HDIM * HDIM + i] = W2[i];
        sW[2 * HDIM * HDIM + i] = W3[i];
    }
    __syncthreads();

    int f0 = (tid & 15) * 4;
    int n0 = blockIdx.x * 64 + (tid >> 4) * 4;

    float acc[3][4][4];
#pragma unroll
    for (int m = 0; m < 3; ++m)
#pragma unroll
        for (int j = 0; j < 4; ++j)
#pragma unroll
            for (int c = 0; c < 4; ++c) acc[m][j][c] = 0.f;

    for (int k4 = 0; k4 < HDIM; k4 += 4) {
        float hr[4][4];
#pragma unroll
        for (int j = 0; j < 4; ++j) {
            int n = n0 + j;
            if (n < N_NODES) {
                float4 v = *(const float4*)(h + n * HDIM + k4);
                hr[j][0] = v.x; hr[j][1] = v.y; hr[j][2] = v.z; hr[j][3] = v.w;
            } else {
                hr[j][0] = hr[j][1] = hr[j][2] = hr[j][3] = 0.f;
            }
        }
#pragma unroll
        for (int kk = 0; kk < 4; ++kk) {
            int k = k4 + kk;
            float4 w1 = *(const float4*)&sW[k * HDIM + f0];
            float4 w2 = *(const float4*)&sW[HDIM * HDIM + k * HDIM + f0];
            float4 w3 = *(const float4*)&sW[2 * HDIM * HDIM + k * HDIM + f0];
#pragma unroll
            for (int j = 0; j < 4; ++j) {
                float hv = hr[j][kk];
                acc[0][j][0] += hv * w1.x; acc[0][j][1] += hv * w1.y;
                acc[0][j][2] += hv * w1.z; acc[0][j][3] += hv * w1.w;
                acc[1][j][0] += hv * w2.x; acc[1][j][1] += hv * w2.y;
                acc[1][j][2] += hv * w2.z; acc[1][j][3] += hv * w2.w;
                acc[2][j][0] += hv * w3.x; acc[2][j][1] += hv * w3.y;
                acc[2][j][2] += hv * w3.z; acc[2][j][3] += hv * w3.w;
            }
        }
    }

#pragma unroll
    for (int j = 0; j < 4; ++j) {
        int n = n0 + j;
        if (n >= N_NODES) continue;
        float ws = wsum[n];
        float4 av, dv;
        av.x = acc[0][j][0] + b1[f0 + 0];
        av.y = acc[0][j][1] + b1[f0 + 1];
        av.z = acc[0][j][2] + b1[f0 + 2];
        av.w = acc[0][j][3] + b1[f0 + 3];
        dv.x = acc[2][j][0] + b3[f0 + 0] - acc[1][j][0] * ws;
        dv.y = acc[2][j][1] + b3[f0 + 1] - acc[1][j][1] * ws;
        dv.z = acc[2][j][2] + b3[f0 + 2] - acc[1][j][2] * ws;
        dv.w = acc[2][j][3] + b3[f0 + 3] - acc[1][j][3] * ws;
        *(float4*)(a_out + n * HDIM + f0) = av;
        *(float4*)(d_out_ + n * HDIM + f0) = dv;
    }
}

// ---------------- CSR aggregate + relu: h = relu(sum_j a[src_j]*w_j + d) ----------------
__global__ __launch_bounds__(256) void k_agg(const int2* __restrict__ edge2,
                                             const int* __restrict__ off,
                                             const float* __restrict__ a,
                                             const float* __restrict__ dbuf,
                                             float* __restrict__ h) {
    int wid = threadIdx.x >> 6;
    int lane = threadIdx.x & 63;
    int n = blockIdx.x * 4 + wid;
    if (n >= N_NODES) return;
    int lo = off[n], hi = off[n + 1];
    float acc = 0.f;
    for (int j0 = lo; j0 < hi; j0 += 64) {
        int idx = 0;
        float w = 0.f;
        if (j0 + lane < hi) {
            int2 p = edge2[j0 + lane];
            idx = p.x;
            w = __int_as_float(p.y);
        }
        int cnt = min(64, hi - j0);
        for (int k = 0; k < cnt; ++k) {
            int s = __shfl(idx, k);
            float ww = __shfl(w, k);
            acc += a[(size_t)s * HDIM + lane] * ww;
        }
    }
    size_t o = (size_t)n * HDIM + lane;
    h[o] = fmaxf(acc + dbuf[o], 0.f);
}

// ---------------- graph boundaries from sorted batch ----------------
__global__ void k_bounds(const int* __restrict__ batch, int* __restrict__ goff) {
    int n = blockIdx.x * blockDim.x + threadIdx.x;
    if (n >= N_NODES) return;
    int b = batch[n];
    int bp = (n == 0) ? -1 : batch[n - 1];
    for (int g = bp + 1; g <= b; ++g) goff[g] = n;
    if (n == N_NODES - 1) {
        for (int g = b + 1; g <= G_GRAPHS; ++g) goff[g] = N_NODES;
    }
}

// ---------------- mean pool: one wave per graph ----------------
__global__ __launch_bounds__(64) void k_pool(const float* __restrict__ h,
                                             const int* __restrict__ goff,
                                             float* __restrict__ gx) {
    int g = blockIdx.x;
    int lane = threadIdx.x;
    int lo = goff[g], hi = goff[g + 1];
    float acc = 0.f;
    for (int n = lo; n < hi; ++n) acc += h[(size_t)n * HDIM + lane];
    float cnt = (float)(hi - lo);
    gx[g * HDIM + lane] = acc / fmaxf(cnt, 1.f);
}

// ---------------- head: out = relu(gx@W1+b1)@W2+b2 ----------------
__global__ __launch_bounds__(128) void k_head(const float* __restrict__ gx,
                                              const float* __restrict__ W1,
                                              const float* __restrict__ b1,
                                              const float* __restrict__ W2,
                                              const float* __restrict__ b2,
                                              float* __restrict__ out) {
    int g = blockIdx.x;
    __shared__ float sx[HDIM];
    __shared__ float sy[2 * HDIM];
    int tid = threadIdx.x;
    if (tid < HDIM) sx[tid] = gx[g * HDIM + tid];
    __syncthreads();
    float acc = b1[tid];
    for (int k = 0; k < HDIM; ++k) acc += sx[k] * W1[k * 2 * HDIM + tid];
    sy[tid] = fmaxf(acc, 0.f);
    __syncthreads();
    if (tid < C_CLS) {
        float o = b2[tid];
        for (int k = 0; k < 2 * HDIM; ++k) o += sy[k] * W2[k * C_CLS + tid];
        out[g * C_CLS + tid] = o;
    }
}

extern "C" void kernel_launch(void* const* d_in, const int* in_sizes, int n_in,
                              void* d_out, int out_size, void* d_ws, size_t ws_size,
                              hipStream_t stream) {
    const float* x      = (const float*)d_in[0];
    const int*   ei     = (const int*)d_in[1];
    const float* eattr  = (const float*)d_in[2];
    const int*   batch  = (const int*)d_in[3];
    const float* w_emb  = (const float*)d_in[4];
    const float* b_emb  = (const float*)d_in[5];
    const float* lin1_w = (const float*)d_in[6];
    const float* lin1_b = (const float*)d_in[7];
    const float* lin2_w = (const float*)d_in[8];
    const float* lin3_w = (const float*)d_in[9];
    const float* lin3_b = (const float*)d_in[10];
    const float* mlp_w1 = (const float*)d_in[11];
    const float* mlp_b1 = (const float*)d_in[12];
    const float* mlp_w2 = (const float*)d_in[13];
    const float* mlp_b2 = (const float*)d_in[14];
    float* out = (float*)d_out;

    const int* src = ei;
    const int* dst = ei + N_EDGES;

    const size_t NH = (size_t)N_NODES * HDIM;
    float* fws = (float*)d_ws;
    float* h    = fws;                 // NH
    float* a    = h + NH;              // NH
    float* dbuf = a + NH;              // NH
    float* wsum = dbuf + NH;           // N
    float* gx   = wsum + N_NODES;      // G*H
    int2* edge2 = (int2*)(gx + (size_t)G_GRAPHS * HDIM);  // E (8B each)
    int2* bbuf  = edge2 + N_EDGES;     // E
    int* off    = (int*)(bbuf + N_EDGES);  // N+1
    int* bcnt   = off + N_NODES + 1;   // NB (zeroed)
    int* bcur   = bcnt + NB;           // NB
    int* boff   = bcur + NB;           // NB+1
    int* goff   = boff + NB + 1;       // G+1

    hipMemsetAsync(bcnt, 0, NB * sizeof(int), stream);

    int nh_blocks = (N_NODES * HDIM + 255) / 256;
    int n_blocks = (N_NODES + 255) / 256;

    k_emb<<<nh_blocks, 256, 0, stream>>>(x, w_emb, b_emb, h);
    k_hist<<<512, 256, 0, stream>>>(dst, bcnt);
    k_boff<<<1, 256, 0, stream>>>(bcnt, boff, bcur);
    k_bucket<<<CBLK, 1024, 0, stream>>>(src, dst, eattr, bcur, bbuf);
    k_csr<<<NB, 256, 0, stream>>>(bbuf, boff, off, wsum, edge2);
    k_bounds<<<n_blocks, 256, 0, stream>>>(batch, goff);

    int gemm_blocks = (N_NODES + 63) / 64;
    int agg_blocks = (N_NODES + 3) / 4;

    for (int l = 0; l < 2; ++l) {
        const float* W1 = lin1_w + l * HDIM * HDIM;
        const float* B1 = lin1_b + l * HDIM;
        const float* W2 = lin2_w + l * HDIM * HDIM;
        const float* W3 = lin3_w + l * HDIM * HDIM;
        const float* B3 = lin3_b + l * HDIM;
        k_gemm3<<<gemm_blocks, 256, 0, stream>>>(h, W1, B1, W2, W3, B3, wsum, a, dbuf);
        k_agg<<<agg_blocks, 256, 0, stream>>>(edge2, off, a, dbuf, h);
    }

    k_pool<<<G_GRAPHS, 64, 0, stream>>>(h, goff, gx);
    k_head<<<G_GRAPHS, 128, 0, stream>>>(gx, mlp_w1, mlp_b1, mlp_w2, mlp_b2, out);
}

// Round 4
// 373.396 us; speedup vs baseline: 2.8341x; 1.2134x over previous
//
#include <hip/hip_runtime.h>

#define N_NODES 100000
#define N_EDGES 1600000
#define F_INPUT 4
#define HDIM 64
#define G_GRAPHS 1000
#define C_CLS 3

#define NPB 512          // nodes per bucket (power of 2)
#define BSHIFT 9
#define NB 196           // ceil(N_NODES / NPB)
#define CBLK 391         // ceil(N_EDGES / 4096)

// ---------------- embedding: h = x @ w_emb + b_emb ----------------
__global__ void k_emb(const float* __restrict__ x, const float* __restrict__ w,
                      const float* __restrict__ b, float* __restrict__ h) {
    int t = blockIdx.x * blockDim.x + threadIdx.x;
    if (t >= N_NODES * HDIM) return;
    int n = t >> 6, f = t & 63;
    const float* xr = x + n * F_INPUT;
    float acc = b[f];
#pragma unroll
    for (int k = 0; k < F_INPUT; ++k) acc += xr[k] * w[k * HDIM + f];
    h[t] = acc;
}

// ---------------- bucket histogram (LDS-aggregated) ----------------
__global__ __launch_bounds__(256) void k_hist(const int* __restrict__ dst,
                                              int* __restrict__ bcnt) {
    __shared__ int s[NB];
    for (int i = threadIdx.x; i < NB; i += 256) s[i] = 0;
    __syncthreads();
    for (int e = blockIdx.x * 256 + threadIdx.x; e < N_EDGES; e += 512 * 256)
        atomicAdd(&s[dst[e] >> BSHIFT], 1);
    __syncthreads();
    for (int i = threadIdx.x; i < NB; i += 256)
        if (s[i]) atomicAdd(&bcnt[i], s[i]);
}

// ---------------- bucket offsets: scan of 196 values ----------------
__global__ __launch_bounds__(256) void k_boff(const int* __restrict__ bcnt,
                                              int* __restrict__ boff,
                                              int* __restrict__ bcur) {
    __shared__ int s[256];
    int t = threadIdx.x;
    int v = (t < NB) ? bcnt[t] : 0;
    s[t] = v;
    __syncthreads();
    for (int d = 1; d < 256; d <<= 1) {
        int x = (t >= d) ? s[t - d] : 0;
        __syncthreads();
        s[t] += x;
        __syncthreads();
    }
    int ex = s[t] - v;
    if (t < NB) { boff[t] = ex; bcur[t] = ex; }
    if (t == 0) boff[NB] = N_EDGES;
}

// ---------------- scatter edges into buckets (packed 8B records) ----------------
// record: x = src | (dloc << 17) ; y = bits of w
__global__ __launch_bounds__(1024) void k_bucket(const int* __restrict__ src,
                                                 const int* __restrict__ dst,
                                                 const float* __restrict__ attr,
                                                 int* __restrict__ bcur,
                                                 int2* __restrict__ bbuf) {
    __shared__ int cnt[NB];
    __shared__ int base[NB];
    for (int i = threadIdx.x; i < NB; i += 1024) cnt[i] = 0;
    __syncthreads();
    int e0 = blockIdx.x * 4096;
    int myb[4], myrank[4];
    int2 mypack[4];
#pragma unroll
    for (int k = 0; k < 4; ++k) {
        int e = e0 + k * 1024 + threadIdx.x;
        if (e < N_EDGES) {
            int d = dst[e];
            int b = d >> BSHIFT;
            myb[k] = b;
            myrank[k] = atomicAdd(&cnt[b], 1);
            mypack[k].x = src[e] | ((d & (NPB - 1)) << 17);
            mypack[k].y = __float_as_int(attr[e]);
        } else
            myb[k] = -1;
    }
    __syncthreads();
    for (int i = threadIdx.x; i < NB; i += 1024)
        base[i] = cnt[i] ? atomicAdd(&bcur[i], cnt[i]) : 0;
    __syncthreads();
#pragma unroll
    for (int k = 0; k < 4; ++k)
        if (myb[k] >= 0) bbuf[base[myb[k]] + myrank[k]] = mypack[k];
}

// ---------------- per-bucket CSR finalize: off, wsum, sorted edge2 ----------------
__global__ __launch_bounds__(256) void k_csr(const int2* __restrict__ bbuf,
                                             const int* __restrict__ boff,
                                             int* __restrict__ off,
                                             float* __restrict__ wsum,
                                             int2* __restrict__ edge2) {
    __shared__ int deg[NPB];
    __shared__ float wsm[NPB];
    __shared__ int loff[NPB];
    __shared__ int sct[256];
    int b = blockIdx.x;
    int lo = boff[b], hi = boff[b + 1];
    int t = threadIdx.x;
    for (int i = t; i < NPB; i += 256) { deg[i] = 0; wsm[i] = 0.f; }
    __syncthreads();
    for (int j = lo + t; j < hi; j += 256) {
        int2 p = bbuf[j];
        int dloc = (p.x >> 17) & (NPB - 1);
        atomicAdd(&deg[dloc], 1);
        atomicAdd(&wsm[dloc], __int_as_float(p.y));
    }
    __syncthreads();
    // exclusive scan of deg[512] (2 per thread)
    int v0 = deg[2 * t], v1 = deg[2 * t + 1];
    int tot = v0 + v1;
    sct[t] = tot;
    __syncthreads();
    for (int d = 1; d < 256; d <<= 1) {
        int x = (t >= d) ? sct[t - d] : 0;
        __syncthreads();
        sct[t] += x;
        __syncthreads();
    }
    int ex = sct[t] - tot;
    loff[2 * t] = ex;
    loff[2 * t + 1] = ex + v0;
    __syncthreads();
    int nbase = b * NPB;
    for (int i = t; i < NPB; i += 256) {
        int n = nbase + i;
        if (n < N_NODES) { off[n] = lo + loff[i]; wsum[n] = wsm[i]; }
    }
    if (b == NB - 1 && t == 0) off[N_NODES] = N_EDGES;
    // reuse deg as cursor
    for (int i = t; i < NPB; i += 256) deg[i] = 0;
    __syncthreads();
    for (int j = lo + t; j < hi; j += 256) {
        int2 p = bbuf[j];
        int dloc = (p.x >> 17) & (NPB - 1);
        int r = atomicAdd(&deg[dloc], 1);
        edge2[lo + loff[dloc] + r] = make_int2(p.x & 0x1FFFF, p.y);
    }
}

// ---------------- fused 3-GEMM: a = hW1+b1 ; d = hW3+b3 - (hW2)*wsum ----------------
__global__ __launch_bounds__(256) void k_gemm3(
    const float* __restrict__ h,
    const float* __restrict__ W1, const float* __restrict__ b1,
    const float* __restrict__ W2,
    const float* __restrict__ W3, const float* __restrict__ b3,
    const float* __restrict__ wsum,
    float* __restrict__ a_out, float* __restrict__ d_out_) {
    __shared__ float sW[3 * HDIM * HDIM];  // 48 KB
    int tid = threadIdx.x;
    for (int i = tid; i < HDIM * HDIM; i += 256) {
        sW[i] = W1[i];
        sW[HDIM * HDIM + i] = W2[i];
        sW[2 * HDIM * HDIM + i] = W3[i];
    }
    __syncthreads();

    int f0 = (tid & 15) * 4;
    int n0 = blockIdx.x * 64 + (tid >> 4) * 4;

    float acc[3][4][4];
#pragma unroll
    for (int m = 0; m < 3; ++m)
#pragma unroll
        for (int j = 0; j < 4; ++j)
#pragma unroll
            for (int c = 0; c < 4; ++c) acc[m][j][c] = 0.f;

    for (int k4 = 0; k4 < HDIM; k4 += 4) {
        float hr[4][4];
#pragma unroll
        for (int j = 0; j < 4; ++j) {
            int n = n0 + j;
            if (n < N_NODES) {
                float4 v = *(const float4*)(h + n * HDIM + k4);
                hr[j][0] = v.x; hr[j][1] = v.y; hr[j][2] = v.z; hr[j][3] = v.w;
            } else {
                hr[j][0] = hr[j][1] = hr[j][2] = hr[j][3] = 0.f;
            }
        }
#pragma unroll
        for (int kk = 0; kk < 4; ++kk) {
            int k = k4 + kk;
            float4 w1 = *(const float4*)&sW[k * HDIM + f0];
            float4 w2 = *(const float4*)&sW[HDIM * HDIM + k * HDIM + f0];
            float4 w3 = *(const float4*)&sW[2 * HDIM * HDIM + k * HDIM + f0];
#pragma unroll
            for (int j = 0; j < 4; ++j) {
                float hv = hr[j][kk];
                acc[0][j][0] += hv * w1.x; acc[0][j][1] += hv * w1.y;
                acc[0][j][2] += hv * w1.z; acc[0][j][3] += hv * w1.w;
                acc[1][j][0] += hv * w2.x; acc[1][j][1] += hv * w2.y;
                acc[1][j][2] += hv * w2.z; acc[1][j][3] += hv * w2.w;
                acc[2][j][0] += hv * w3.x; acc[2][j][1] += hv * w3.y;
                acc[2][j][2] += hv * w3.z; acc[2][j][3] += hv * w3.w;
            }
        }
    }

#pragma unroll
    for (int j = 0; j < 4; ++j) {
        int n = n0 + j;
        if (n >= N_NODES) continue;
        float ws = wsum[n];
        float4 av, dv;
        av.x = acc[0][j][0] + b1[f0 + 0];
        av.y = acc[0][j][1] + b1[f0 + 1];
        av.z = acc[0][j][2] + b1[f0 + 2];
        av.w = acc[0][j][3] + b1[f0 + 3];
        dv.x = acc[2][j][0] + b3[f0 + 0] - acc[1][j][0] * ws;
        dv.y = acc[2][j][1] + b3[f0 + 1] - acc[1][j][1] * ws;
        dv.z = acc[2][j][2] + b3[f0 + 2] - acc[1][j][2] * ws;
        dv.w = acc[2][j][3] + b3[f0 + 3] - acc[1][j][3] * ws;
        *(float4*)(a_out + n * HDIM + f0) = av;
        *(float4*)(d_out_ + n * HDIM + f0) = dv;
    }
}

// ---------------- CSR aggregate + relu: h = relu(sum_j a[src_j]*w_j + d) ----------------
// Quarter-wave layout: 4 edge slots x 16 lanes, float4 per lane.
__global__ __launch_bounds__(256) void k_agg(const int2* __restrict__ edge2,
                                             const int* __restrict__ off,
                                             const float* __restrict__ a,
                                             const float* __restrict__ dbuf,
                                             float* __restrict__ h) {
    int wid = threadIdx.x >> 6;
    int lane = threadIdx.x & 63;
    int slot = lane >> 4;        // 0..3
    int fq = lane & 15;          // feature quad: floats [fq*4, fq*4+4)
    int n = blockIdx.x * 4 + wid;
    if (n >= N_NODES) return;
    int lo = off[n], hi = off[n + 1];

    float4 acc0 = {0.f, 0.f, 0.f, 0.f};
    float4 acc1 = {0.f, 0.f, 0.f, 0.f};
    int j = lo + slot;
    // unrolled x2: 8 edges per wave-iteration, 2 independent row loads per lane
    for (; j + 4 < hi; j += 8) {
        int2 p0 = edge2[j];
        int2 p1 = edge2[j + 4];
        float w0 = __int_as_float(p0.y);
        float w1 = __int_as_float(p1.y);
        float4 v0 = *(const float4*)(a + (size_t)p0.x * HDIM + fq * 4);
        float4 v1 = *(const float4*)(a + (size_t)p1.x * HDIM + fq * 4);
        acc0.x += v0.x * w0; acc0.y += v0.y * w0; acc0.z += v0.z * w0; acc0.w += v0.w * w0;
        acc1.x += v1.x * w1; acc1.y += v1.y * w1; acc1.z += v1.z * w1; acc1.w += v1.w * w1;
    }
    if (j < hi) {
        int2 p0 = edge2[j];
        float w0 = __int_as_float(p0.y);
        float4 v0 = *(const float4*)(a + (size_t)p0.x * HDIM + fq * 4);
        acc0.x += v0.x * w0; acc0.y += v0.y * w0; acc0.z += v0.z * w0; acc0.w += v0.w * w0;
    }
    acc0.x += acc1.x; acc0.y += acc1.y; acc0.z += acc1.z; acc0.w += acc1.w;

    // reduce the 4 slots: lanes differing in bits 4,5 hold partials of same fq
    acc0.x += __shfl_xor(acc0.x, 16); acc0.y += __shfl_xor(acc0.y, 16);
    acc0.z += __shfl_xor(acc0.z, 16); acc0.w += __shfl_xor(acc0.w, 16);
    acc0.x += __shfl_xor(acc0.x, 32); acc0.y += __shfl_xor(acc0.y, 32);
    acc0.z += __shfl_xor(acc0.z, 32); acc0.w += __shfl_xor(acc0.w, 32);

    if (slot == 0) {
        float4 dv = *(const float4*)(dbuf + (size_t)n * HDIM + fq * 4);
        float4 o;
        o.x = fmaxf(acc0.x + dv.x, 0.f);
        o.y = fmaxf(acc0.y + dv.y, 0.f);
        o.z = fmaxf(acc0.z + dv.z, 0.f);
        o.w = fmaxf(acc0.w + dv.w, 0.f);
        *(float4*)(h + (size_t)n * HDIM + fq * 4) = o;
    }
}

// ---------------- graph boundaries from sorted batch ----------------
__global__ void k_bounds(const int* __restrict__ batch, int* __restrict__ goff) {
    int n = blockIdx.x * blockDim.x + threadIdx.x;
    if (n >= N_NODES) return;
    int b = batch[n];
    int bp = (n == 0) ? -1 : batch[n - 1];
    for (int g = bp + 1; g <= b; ++g) goff[g] = n;
    if (n == N_NODES - 1) {
        for (int g = b + 1; g <= G_GRAPHS; ++g) goff[g] = N_NODES;
    }
}

// ---------------- mean pool: one wave per graph ----------------
__global__ __launch_bounds__(64) void k_pool(const float* __restrict__ h,
                                             const int* __restrict__ goff,
                                             float* __restrict__ gx) {
    int g = blockIdx.x;
    int lane = threadIdx.x;
    int lo = goff[g], hi = goff[g + 1];
    float acc = 0.f;
    for (int n = lo; n < hi; ++n) acc += h[(size_t)n * HDIM + lane];
    float cnt = (float)(hi - lo);
    gx[g * HDIM + lane] = acc / fmaxf(cnt, 1.f);
}

// ---------------- head: out = relu(gx@W1+b1)@W2+b2 ----------------
__global__ __launch_bounds__(128) void k_head(const float* __restrict__ gx,
                                              const float* __restrict__ W1,
                                              const float* __restrict__ b1,
                                              const float* __restrict__ W2,
                                              const float* __restrict__ b2,
                                              float* __restrict__ out) {
    int g = blockIdx.x;
    __shared__ float sx[HDIM];
    __shared__ float sy[2 * HDIM];
    int tid = threadIdx.x;
    if (tid < HDIM) sx[tid] = gx[g * HDIM + tid];
    __syncthreads();
    float acc = b1[tid];
    for (int k = 0; k < HDIM; ++k) acc += sx[k] * W1[k * 2 * HDIM + tid];
    sy[tid] = fmaxf(acc, 0.f);
    __syncthreads();
    if (tid < C_CLS) {
        float o = b2[tid];
        for (int k = 0; k < 2 * HDIM; ++k) o += sy[k] * W2[k * C_CLS + tid];
        out[g * C_CLS + tid] = o;
    }
}

extern "C" void kernel_launch(void* const* d_in, const int* in_sizes, int n_in,
                              void* d_out, int out_size, void* d_ws, size_t ws_size,
                              hipStream_t stream) {
    const float* x      = (const float*)d_in[0];
    const int*   ei     = (const int*)d_in[1];
    const float* eattr  = (const float*)d_in[2];
    const int*   batch  = (const int*)d_in[3];
    const float* w_emb  = (const float*)d_in[4];
    const float* b_emb  = (const float*)d_in[5];
    const float* lin1_w = (const float*)d_in[6];
    const float* lin1_b = (const float*)d_in[7];
    const float* lin2_w = (const float*)d_in[8];
    const float* lin3_w = (const float*)d_in[9];
    const float* lin3_b = (const float*)d_in[10];
    const float* mlp_w1 = (const float*)d_in[11];
    const float* mlp_b1 = (const float*)d_in[12];
    const float* mlp_w2 = (const float*)d_in[13];
    const float* mlp_b2 = (const float*)d_in[14];
    float* out = (float*)d_out;

    const int* src = ei;
    const int* dst = ei + N_EDGES;

    const size_t NH = (size_t)N_NODES * HDIM;
    float* fws = (float*)d_ws;
    float* h    = fws;                 // NH
    float* a    = h + NH;              // NH
    float* dbuf = a + NH;              // NH
    float* wsum = dbuf + NH;           // N
    float* gx   = wsum + N_NODES;      // G*H
    int2* edge2 = (int2*)(gx + (size_t)G_GRAPHS * HDIM);  // E (8B each)
    int2* bbuf  = edge2 + N_EDGES;     // E
    int* off    = (int*)(bbuf + N_EDGES);  // N+1
    int* bcnt   = off + N_NODES + 1;   // NB (zeroed)
    int* bcur   = bcnt + NB;           // NB
    int* boff   = bcur + NB;           // NB+1
    int* goff   = boff + NB + 1;       // G+1

    hipMemsetAsync(bcnt, 0, NB * sizeof(int), stream);

    int nh_blocks = (N_NODES * HDIM + 255) / 256;
    int n_blocks = (N_NODES + 255) / 256;

    k_emb<<<nh_blocks, 256, 0, stream>>>(x, w_emb, b_emb, h);
    k_hist<<<512, 256, 0, stream>>>(dst, bcnt);
    k_boff<<<1, 256, 0, stream>>>(bcnt, boff, bcur);
    k_bucket<<<CBLK, 1024, 0, stream>>>(src, dst, eattr, bcur, bbuf);
    k_csr<<<NB, 256, 0, stream>>>(bbuf, boff, off, wsum, edge2);
    k_bounds<<<n_blocks, 256, 0, stream>>>(batch, goff);

    int gemm_blocks = (N_NODES + 63) / 64;
    int agg_blocks = (N_NODES + 3) / 4;

    for (int l = 0; l < 2; ++l) {
        const float* W1 = lin1_w + l * HDIM * HDIM;
        const float* B1 = lin1_b + l * HDIM;
        const float* W2 = lin2_w + l * HDIM * HDIM;
        const float* W3 = lin3_w + l * HDIM * HDIM;
        const float* B3 = lin3_b + l * HDIM;
        k_gemm3<<<gemm_blocks, 256, 0, stream>>>(h, W1, B1, W2, W3, B3, wsum, a, dbuf);
        k_agg<<<agg_blocks, 256, 0, stream>>>(edge2, off, a, dbuf, h);
    }

    k_pool<<<G_GRAPHS, 64, 0, stream>>>(h, goff, gx);
    k_head<<<G_GRAPHS, 128, 0, stream>>>(gx, mlp_w1, mlp_b1, mlp_w2, mlp_b2, out);
}

// Round 5
// 344.700 us; speedup vs baseline: 3.0701x; 1.0833x over previous
//
#include <hip/hip_runtime.h>

#define N_NODES 100000
#define N_EDGES 1600000
#define F_INPUT 4
#define HDIM 64
#define G_GRAPHS 1000
#define C_CLS 3

#define NPB 512          // nodes per bucket (power of 2)
#define BSHIFT 9
#define NB 196           // ceil(N_NODES / NPB)
#define CBLK 391         // ceil(N_EDGES / 4096)

__device__ __forceinline__ unsigned short f2bf(float f) {
    unsigned u = __float_as_uint(f);
    unsigned r = (u + 0x7FFF + ((u >> 16) & 1)) >> 16;  // round-to-nearest-even
    return (unsigned short)r;
}
__device__ __forceinline__ float bf2f(unsigned short b) {
    return __uint_as_float(((unsigned)b) << 16);
}

// ---------------- embedding: h = x @ w_emb + b_emb ----------------
__global__ void k_emb(const float* __restrict__ x, const float* __restrict__ w,
                      const float* __restrict__ b, float* __restrict__ h) {
    int t = blockIdx.x * blockDim.x + threadIdx.x;
    if (t >= N_NODES * HDIM) return;
    int n = t >> 6, f = t & 63;
    const float* xr = x + n * F_INPUT;
    float acc = b[f];
#pragma unroll
    for (int k = 0; k < F_INPUT; ++k) acc += xr[k] * w[k * HDIM + f];
    h[t] = acc;
}

// ---------------- bucket histogram (LDS-aggregated) ----------------
__global__ __launch_bounds__(256) void k_hist(const int* __restrict__ dst,
                                              int* __restrict__ bcnt) {
    __shared__ int s[NB];
    for (int i = threadIdx.x; i < NB; i += 256) s[i] = 0;
    __syncthreads();
    for (int e = blockIdx.x * 256 + threadIdx.x; e < N_EDGES; e += 512 * 256)
        atomicAdd(&s[dst[e] >> BSHIFT], 1);
    __syncthreads();
    for (int i = threadIdx.x; i < NB; i += 256)
        if (s[i]) atomicAdd(&bcnt[i], s[i]);
}

// ---------------- bucket offsets: scan of 196 values ----------------
__global__ __launch_bounds__(256) void k_boff(const int* __restrict__ bcnt,
                                              int* __restrict__ boff,
                                              int* __restrict__ bcur) {
    __shared__ int s[256];
    int t = threadIdx.x;
    int v = (t < NB) ? bcnt[t] : 0;
    s[t] = v;
    __syncthreads();
    for (int d = 1; d < 256; d <<= 1) {
        int x = (t >= d) ? s[t - d] : 0;
        __syncthreads();
        s[t] += x;
        __syncthreads();
    }
    int ex = s[t] - v;
    if (t < NB) { boff[t] = ex; bcur[t] = ex; }
    if (t == 0) boff[NB] = N_EDGES;
}

// ---------------- scatter edges into buckets (packed 8B records) ----------------
// record: x = src | (dloc << 17) ; y = bits of w
__global__ __launch_bounds__(1024) void k_bucket(const int* __restrict__ src,
                                                 const int* __restrict__ dst,
                                                 const float* __restrict__ attr,
                                                 int* __restrict__ bcur,
                                                 int2* __restrict__ bbuf) {
    __shared__ int cnt[NB];
    __shared__ int base[NB];
    for (int i = threadIdx.x; i < NB; i += 1024) cnt[i] = 0;
    __syncthreads();
    int e0 = blockIdx.x * 4096;
    int myb[4], myrank[4];
    int2 mypack[4];
#pragma unroll
    for (int k = 0; k < 4; ++k) {
        int e = e0 + k * 1024 + threadIdx.x;
        if (e < N_EDGES) {
            int d = dst[e];
            int b = d >> BSHIFT;
            myb[k] = b;
            myrank[k] = atomicAdd(&cnt[b], 1);
            mypack[k].x = src[e] | ((d & (NPB - 1)) << 17);
            mypack[k].y = __float_as_int(attr[e]);
        } else
            myb[k] = -1;
    }
    __syncthreads();
    for (int i = threadIdx.x; i < NB; i += 1024)
        base[i] = cnt[i] ? atomicAdd(&bcur[i], cnt[i]) : 0;
    __syncthreads();
#pragma unroll
    for (int k = 0; k < 4; ++k)
        if (myb[k] >= 0) bbuf[base[myb[k]] + myrank[k]] = mypack[k];
}

// ---------------- per-bucket CSR finalize: off, wsum, sorted edge2 ----------------
__global__ __launch_bounds__(256) void k_csr(const int2* __restrict__ bbuf,
                                             const int* __restrict__ boff,
                                             int* __restrict__ off,
                                             float* __restrict__ wsum,
                                             int2* __restrict__ edge2) {
    __shared__ int deg[NPB];
    __shared__ float wsm[NPB];
    __shared__ int loff[NPB];
    __shared__ int sct[256];
    int b = blockIdx.x;
    int lo = boff[b], hi = boff[b + 1];
    int t = threadIdx.x;
    for (int i = t; i < NPB; i += 256) { deg[i] = 0; wsm[i] = 0.f; }
    __syncthreads();
    for (int j = lo + t; j < hi; j += 256) {
        int2 p = bbuf[j];
        int dloc = (p.x >> 17) & (NPB - 1);
        atomicAdd(&deg[dloc], 1);
        atomicAdd(&wsm[dloc], __int_as_float(p.y));
    }
    __syncthreads();
    // exclusive scan of deg[512] (2 per thread)
    int v0 = deg[2 * t], v1 = deg[2 * t + 1];
    int tot = v0 + v1;
    sct[t] = tot;
    __syncthreads();
    for (int d = 1; d < 256; d <<= 1) {
        int x = (t >= d) ? sct[t - d] : 0;
        __syncthreads();
        sct[t] += x;
        __syncthreads();
    }
    int ex = sct[t] - tot;
    loff[2 * t] = ex;
    loff[2 * t + 1] = ex + v0;
    __syncthreads();
    int nbase = b * NPB;
    for (int i = t; i < NPB; i += 256) {
        int n = nbase + i;
        if (n < N_NODES) { off[n] = lo + loff[i]; wsum[n] = wsm[i]; }
    }
    if (b == NB - 1 && t == 0) off[N_NODES] = N_EDGES;
    // reuse deg as cursor
    for (int i = t; i < NPB; i += 256) deg[i] = 0;
    __syncthreads();
    for (int j = lo + t; j < hi; j += 256) {
        int2 p = bbuf[j];
        int dloc = (p.x >> 17) & (NPB - 1);
        int r = atomicAdd(&deg[dloc], 1);
        edge2[lo + loff[dloc] + r] = make_int2(p.x & 0x1FFFF, p.y);
    }
}

// ---------------- fused 3-GEMM: a(bf16) = hW1+b1 ; d = hW3+b3 - (hW2)*wsum ----------------
__global__ __launch_bounds__(256) void k_gemm3(
    const float* __restrict__ h,
    const float* __restrict__ W1, const float* __restrict__ b1,
    const float* __restrict__ W2,
    const float* __restrict__ W3, const float* __restrict__ b3,
    const float* __restrict__ wsum,
    unsigned short* __restrict__ a_out, float* __restrict__ d_out_) {
    __shared__ float sW[3 * HDIM * HDIM];  // 48 KB
    int tid = threadIdx.x;
    for (int i = tid; i < HDIM * HDIM; i += 256) {
        sW[i] = W1[i];
        sW[HDIM * HDIM + i] = W2[i];
        sW[2 * HDIM * HDIM + i] = W3[i];
    }
    __syncthreads();

    int f0 = (tid & 15) * 4;
    int n0 = blockIdx.x * 64 + (tid >> 4) * 4;

    float acc[3][4][4];
#pragma unroll
    for (int m = 0; m < 3; ++m)
#pragma unroll
        for (int j = 0; j < 4; ++j)
#pragma unroll
            for (int c = 0; c < 4; ++c) acc[m][j][c] = 0.f;

    for (int k4 = 0; k4 < HDIM; k4 += 4) {
        float hr[4][4];
#pragma unroll
        for (int j = 0; j < 4; ++j) {
            int n = n0 + j;
            if (n < N_NODES) {
                float4 v = *(const float4*)(h + n * HDIM + k4);
                hr[j][0] = v.x; hr[j][1] = v.y; hr[j][2] = v.z; hr[j][3] = v.w;
            } else {
                hr[j][0] = hr[j][1] = hr[j][2] = hr[j][3] = 0.f;
            }
        }
#pragma unroll
        for (int kk = 0; kk < 4; ++kk) {
            int k = k4 + kk;
            float4 w1 = *(const float4*)&sW[k * HDIM + f0];
            float4 w2 = *(const float4*)&sW[HDIM * HDIM + k * HDIM + f0];
            float4 w3 = *(const float4*)&sW[2 * HDIM * HDIM + k * HDIM + f0];
#pragma unroll
            for (int j = 0; j < 4; ++j) {
                float hv = hr[j][kk];
                acc[0][j][0] += hv * w1.x; acc[0][j][1] += hv * w1.y;
                acc[0][j][2] += hv * w1.z; acc[0][j][3] += hv * w1.w;
                acc[1][j][0] += hv * w2.x; acc[1][j][1] += hv * w2.y;
                acc[1][j][2] += hv * w2.z; acc[1][j][3] += hv * w2.w;
                acc[2][j][0] += hv * w3.x; acc[2][j][1] += hv * w3.y;
                acc[2][j][2] += hv * w3.z; acc[2][j][3] += hv * w3.w;
            }
        }
    }

#pragma unroll
    for (int j = 0; j < 4; ++j) {
        int n = n0 + j;
        if (n >= N_NODES) continue;
        float ws = wsum[n];
        ushort4 av;
        float4 dv;
        av.x = f2bf(acc[0][j][0] + b1[f0 + 0]);
        av.y = f2bf(acc[0][j][1] + b1[f0 + 1]);
        av.z = f2bf(acc[0][j][2] + b1[f0 + 2]);
        av.w = f2bf(acc[0][j][3] + b1[f0 + 3]);
        dv.x = acc[2][j][0] + b3[f0 + 0] - acc[1][j][0] * ws;
        dv.y = acc[2][j][1] + b3[f0 + 1] - acc[1][j][1] * ws;
        dv.z = acc[2][j][2] + b3[f0 + 2] - acc[1][j][2] * ws;
        dv.w = acc[2][j][3] + b3[f0 + 3] - acc[1][j][3] * ws;
        *(ushort4*)(a_out + (size_t)n * HDIM + f0) = av;
        *(float4*)(d_out_ + (size_t)n * HDIM + f0) = dv;
    }
}

// ---------------- CSR aggregate + relu: h = relu(sum_j a[src_j]*w_j + d) ----------------
// Quarter-wave layout: 4 edge slots x 16 lanes, bf16x4 per lane (8B).
__global__ __launch_bounds__(256) void k_agg(const int2* __restrict__ edge2,
                                             const int* __restrict__ off,
                                             const unsigned short* __restrict__ a,
                                             const float* __restrict__ dbuf,
                                             float* __restrict__ h) {
    int wid = threadIdx.x >> 6;
    int lane = threadIdx.x & 63;
    int slot = lane >> 4;        // 0..3
    int fq = lane & 15;          // feature quad: floats [fq*4, fq*4+4)
    int n = blockIdx.x * 4 + wid;
    if (n >= N_NODES) return;
    int lo = off[n], hi = off[n + 1];

    float4 acc0 = {0.f, 0.f, 0.f, 0.f};
    float4 acc1 = {0.f, 0.f, 0.f, 0.f};
    int j = lo + slot;
    for (; j + 4 < hi; j += 8) {
        int2 p0 = edge2[j];
        int2 p1 = edge2[j + 4];
        float w0 = __int_as_float(p0.y);
        float w1 = __int_as_float(p1.y);
        ushort4 u0 = *(const ushort4*)(a + (size_t)p0.x * HDIM + fq * 4);
        ushort4 u1 = *(const ushort4*)(a + (size_t)p1.x * HDIM + fq * 4);
        acc0.x += bf2f(u0.x) * w0; acc0.y += bf2f(u0.y) * w0;
        acc0.z += bf2f(u0.z) * w0; acc0.w += bf2f(u0.w) * w0;
        acc1.x += bf2f(u1.x) * w1; acc1.y += bf2f(u1.y) * w1;
        acc1.z += bf2f(u1.z) * w1; acc1.w += bf2f(u1.w) * w1;
    }
    if (j < hi) {
        int2 p0 = edge2[j];
        float w0 = __int_as_float(p0.y);
        ushort4 u0 = *(const ushort4*)(a + (size_t)p0.x * HDIM + fq * 4);
        acc0.x += bf2f(u0.x) * w0; acc0.y += bf2f(u0.y) * w0;
        acc0.z += bf2f(u0.z) * w0; acc0.w += bf2f(u0.w) * w0;
    }
    acc0.x += acc1.x; acc0.y += acc1.y; acc0.z += acc1.z; acc0.w += acc1.w;

    acc0.x += __shfl_xor(acc0.x, 16); acc0.y += __shfl_xor(acc0.y, 16);
    acc0.z += __shfl_xor(acc0.z, 16); acc0.w += __shfl_xor(acc0.w, 16);
    acc0.x += __shfl_xor(acc0.x, 32); acc0.y += __shfl_xor(acc0.y, 32);
    acc0.z += __shfl_xor(acc0.z, 32); acc0.w += __shfl_xor(acc0.w, 32);

    if (slot == 0) {
        float4 dv = *(const float4*)(dbuf + (size_t)n * HDIM + fq * 4);
        float4 o;
        o.x = fmaxf(acc0.x + dv.x, 0.f);
        o.y = fmaxf(acc0.y + dv.y, 0.f);
        o.z = fmaxf(acc0.z + dv.z, 0.f);
        o.w = fmaxf(acc0.w + dv.w, 0.f);
        *(float4*)(h + (size_t)n * HDIM + fq * 4) = o;
    }
}

// ---------------- graph boundaries from sorted batch ----------------
__global__ void k_bounds(const int* __restrict__ batch, int* __restrict__ goff) {
    int n = blockIdx.x * blockDim.x + threadIdx.x;
    if (n >= N_NODES) return;
    int b = batch[n];
    int bp = (n == 0) ? -1 : batch[n - 1];
    for (int g = bp + 1; g <= b; ++g) goff[g] = n;
    if (n == N_NODES - 1) {
        for (int g = b + 1; g <= G_GRAPHS; ++g) goff[g] = N_NODES;
    }
}

// ---------------- mean pool: one wave per graph ----------------
__global__ __launch_bounds__(64) void k_pool(const float* __restrict__ h,
                                             const int* __restrict__ goff,
                                             float* __restrict__ gx) {
    int g = blockIdx.x;
    int lane = threadIdx.x;
    int lo = goff[g], hi = goff[g + 1];
    float acc = 0.f;
    for (int n = lo; n < hi; ++n) acc += h[(size_t)n * HDIM + lane];
    float cnt = (float)(hi - lo);
    gx[g * HDIM + lane] = acc / fmaxf(cnt, 1.f);
}

// ---------------- head: out = relu(gx@W1+b1)@W2+b2 ----------------
__global__ __launch_bounds__(128) void k_head(const float* __restrict__ gx,
                                              const float* __restrict__ W1,
                                              const float* __restrict__ b1,
                                              const float* __restrict__ W2,
                                              const float* __restrict__ b2,
                                              float* __restrict__ out) {
    int g = blockIdx.x;
    __shared__ float sx[HDIM];
    __shared__ float sy[2 * HDIM];
    int tid = threadIdx.x;
    if (tid < HDIM) sx[tid] = gx[g * HDIM + tid];
    __syncthreads();
    float acc = b1[tid];
    for (int k = 0; k < HDIM; ++k) acc += sx[k] * W1[k * 2 * HDIM + tid];
    sy[tid] = fmaxf(acc, 0.f);
    __syncthreads();
    if (tid < C_CLS) {
        float o = b2[tid];
        for (int k = 0; k < 2 * HDIM; ++k) o += sy[k] * W2[k * C_CLS + tid];
        out[g * C_CLS + tid] = o;
    }
}

extern "C" void kernel_launch(void* const* d_in, const int* in_sizes, int n_in,
                              void* d_out, int out_size, void* d_ws, size_t ws_size,
                              hipStream_t stream) {
    const float* x      = (const float*)d_in[0];
    const int*   ei     = (const int*)d_in[1];
    const float* eattr  = (const float*)d_in[2];
    const int*   batch  = (const int*)d_in[3];
    const float* w_emb  = (const float*)d_in[4];
    const float* b_emb  = (const float*)d_in[5];
    const float* lin1_w = (const float*)d_in[6];
    const float* lin1_b = (const float*)d_in[7];
    const float* lin2_w = (const float*)d_in[8];
    const float* lin3_w = (const float*)d_in[9];
    const float* lin3_b = (const float*)d_in[10];
    const float* mlp_w1 = (const float*)d_in[11];
    const float* mlp_b1 = (const float*)d_in[12];
    const float* mlp_w2 = (const float*)d_in[13];
    const float* mlp_b2 = (const float*)d_in[14];
    float* out = (float*)d_out;

    const int* src = ei;
    const int* dst = ei + N_EDGES;

    const size_t NH = (size_t)N_NODES * HDIM;
    float* fws = (float*)d_ws;
    float* h    = fws;                 // NH floats
    float* dbuf = h + NH;              // NH floats
    float* wsum = dbuf + NH;           // N
    float* gx   = wsum + N_NODES;      // G*H
    unsigned short* abf = (unsigned short*)(gx + (size_t)G_GRAPHS * HDIM);  // NH bf16
    int2* edge2 = (int2*)(abf + NH);   // E (8B each)
    int2* bbuf  = edge2 + N_EDGES;     // E
    int* off    = (int*)(bbuf + N_EDGES);  // N+1
    int* bcnt   = off + N_NODES + 1;   // NB (zeroed)
    int* bcur   = bcnt + NB;           // NB
    int* boff   = bcur + NB;           // NB+1
    int* goff   = boff + NB + 1;       // G+1

    hipMemsetAsync(bcnt, 0, NB * sizeof(int), stream);

    int nh_blocks = (N_NODES * HDIM + 255) / 256;
    int n_blocks = (N_NODES + 255) / 256;

    k_emb<<<nh_blocks, 256, 0, stream>>>(x, w_emb, b_emb, h);
    k_hist<<<512, 256, 0, stream>>>(dst, bcnt);
    k_boff<<<1, 256, 0, stream>>>(bcnt, boff, bcur);
    k_bucket<<<CBLK, 1024, 0, stream>>>(src, dst, eattr, bcur, bbuf);
    k_csr<<<NB, 256, 0, stream>>>(bbuf, boff, off, wsum, edge2);
    k_bounds<<<n_blocks, 256, 0, stream>>>(batch, goff);

    int gemm_blocks = (N_NODES + 63) / 64;
    int agg_blocks = (N_NODES + 3) / 4;

    for (int l = 0; l < 2; ++l) {
        const float* W1 = lin1_w + l * HDIM * HDIM;
        const float* B1 = lin1_b + l * HDIM;
        const float* W2 = lin2_w + l * HDIM * HDIM;
        const float* W3 = lin3_w + l * HDIM * HDIM;
        const float* B3 = lin3_b + l * HDIM;
        k_gemm3<<<gemm_blocks, 256, 0, stream>>>(h, W1, B1, W2, W3, B3, wsum, abf, dbuf);
        k_agg<<<agg_blocks, 256, 0, stream>>>(edge2, off, abf, dbuf, h);
    }

    k_pool<<<G_GRAPHS, 64, 0, stream>>>(h, goff, gx);
    k_head<<<G_GRAPHS, 128, 0, stream>>>(gx, mlp_w1, mlp_b1, mlp_w2, mlp_b2, out);
}

// Round 6
// 295.628 us; speedup vs baseline: 3.5797x; 1.1660x over previous
//
#include <hip/hip_runtime.h>

#define N_NODES 100000
#define N_EDGES 1600000
#define F_INPUT 4
#define HDIM 64
#define G_GRAPHS 1000
#define C_CLS 3

#define NPB 512          // nodes per bucket (power of 2)
#define BSHIFT 9
#define NB 196           // ceil(N_NODES / NPB)
#define CBLK 391         // ceil(N_EDGES / 4096)

typedef __attribute__((ext_vector_type(8))) short bf16x8;
typedef __attribute__((ext_vector_type(4))) float f32x4;

__device__ __forceinline__ unsigned short f2bf(float f) {
    unsigned u = __float_as_uint(f);
    unsigned r = (u + 0x7FFF + ((u >> 16) & 1)) >> 16;  // round-to-nearest-even
    return (unsigned short)r;
}
__device__ __forceinline__ float bf2f(unsigned short b) {
    return __uint_as_float(((unsigned)b) << 16);
}

// ---------------- embedding: h = x @ w_emb + b_emb ----------------
__global__ void k_emb(const float* __restrict__ x, const float* __restrict__ w,
                      const float* __restrict__ b, float* __restrict__ h) {
    int t = blockIdx.x * blockDim.x + threadIdx.x;
    if (t >= N_NODES * HDIM) return;
    int n = t >> 6, f = t & 63;
    const float* xr = x + n * F_INPUT;
    float acc = b[f];
#pragma unroll
    for (int k = 0; k < F_INPUT; ++k) acc += xr[k] * w[k * HDIM + f];
    h[t] = acc;
}

// ---------------- bucket histogram (LDS-aggregated) ----------------
__global__ __launch_bounds__(256) void k_hist(const int* __restrict__ dst,
                                              int* __restrict__ bcnt) {
    __shared__ int s[NB];
    for (int i = threadIdx.x; i < NB; i += 256) s[i] = 0;
    __syncthreads();
    for (int e = blockIdx.x * 256 + threadIdx.x; e < N_EDGES; e += 512 * 256)
        atomicAdd(&s[dst[e] >> BSHIFT], 1);
    __syncthreads();
    for (int i = threadIdx.x; i < NB; i += 256)
        if (s[i]) atomicAdd(&bcnt[i], s[i]);
}

// ---------------- bucket offsets: scan of 196 values ----------------
__global__ __launch_bounds__(256) void k_boff(const int* __restrict__ bcnt,
                                              int* __restrict__ boff,
                                              int* __restrict__ bcur) {
    __shared__ int s[256];
    int t = threadIdx.x;
    int v = (t < NB) ? bcnt[t] : 0;
    s[t] = v;
    __syncthreads();
    for (int d = 1; d < 256; d <<= 1) {
        int x = (t >= d) ? s[t - d] : 0;
        __syncthreads();
        s[t] += x;
        __syncthreads();
    }
    int ex = s[t] - v;
    if (t < NB) { boff[t] = ex; bcur[t] = ex; }
    if (t == 0) boff[NB] = N_EDGES;
}

// ---------------- scatter edges into buckets (packed 8B records) ----------------
// record: x = src | (dloc << 17) ; y = bits of w
__global__ __launch_bounds__(1024) void k_bucket(const int* __restrict__ src,
                                                 const int* __restrict__ dst,
                                                 const float* __restrict__ attr,
                                                 int* __restrict__ bcur,
                                                 int2* __restrict__ bbuf) {
    __shared__ int cnt[NB];
    __shared__ int base[NB];
    for (int i = threadIdx.x; i < NB; i += 1024) cnt[i] = 0;
    __syncthreads();
    int e0 = blockIdx.x * 4096;
    int myb[4], myrank[4];
    int2 mypack[4];
#pragma unroll
    for (int k = 0; k < 4; ++k) {
        int e = e0 + k * 1024 + threadIdx.x;
        if (e < N_EDGES) {
            int d = dst[e];
            int b = d >> BSHIFT;
            myb[k] = b;
            myrank[k] = atomicAdd(&cnt[b], 1);
            mypack[k].x = src[e] | ((d & (NPB - 1)) << 17);
            mypack[k].y = __float_as_int(attr[e]);
        } else
            myb[k] = -1;
    }
    __syncthreads();
    for (int i = threadIdx.x; i < NB; i += 1024)
        base[i] = cnt[i] ? atomicAdd(&bcur[i], cnt[i]) : 0;
    __syncthreads();
#pragma unroll
    for (int k = 0; k < 4; ++k)
        if (myb[k] >= 0) bbuf[base[myb[k]] + myrank[k]] = mypack[k];
}

// ---------------- per-bucket CSR finalize: off, wsum, sorted edge2 ----------------
__global__ __launch_bounds__(256) void k_csr(const int2* __restrict__ bbuf,
                                             const int* __restrict__ boff,
                                             int* __restrict__ off,
                                             float* __restrict__ wsum,
                                             int2* __restrict__ edge2) {
    __shared__ int deg[NPB];
    __shared__ float wsm[NPB];
    __shared__ int loff[NPB];
    __shared__ int sct[256];
    int b = blockIdx.x;
    int lo = boff[b], hi = boff[b + 1];
    int t = threadIdx.x;
    for (int i = t; i < NPB; i += 256) { deg[i] = 0; wsm[i] = 0.f; }
    __syncthreads();
    for (int j = lo + t; j < hi; j += 256) {
        int2 p = bbuf[j];
        int dloc = (p.x >> 17) & (NPB - 1);
        atomicAdd(&deg[dloc], 1);
        atomicAdd(&wsm[dloc], __int_as_float(p.y));
    }
    __syncthreads();
    // exclusive scan of deg[512] (2 per thread)
    int v0 = deg[2 * t], v1 = deg[2 * t + 1];
    int tot = v0 + v1;
    sct[t] = tot;
    __syncthreads();
    for (int d = 1; d < 256; d <<= 1) {
        int x = (t >= d) ? sct[t - d] : 0;
        __syncthreads();
        sct[t] += x;
        __syncthreads();
    }
    int ex = sct[t] - tot;
    loff[2 * t] = ex;
    loff[2 * t + 1] = ex + v0;
    __syncthreads();
    int nbase = b * NPB;
    for (int i = t; i < NPB; i += 256) {
        int n = nbase + i;
        if (n < N_NODES) { off[n] = lo + loff[i]; wsum[n] = wsm[i]; }
    }
    if (b == NB - 1 && t == 0) off[N_NODES] = N_EDGES;
    // reuse deg as cursor
    for (int i = t; i < NPB; i += 256) deg[i] = 0;
    __syncthreads();
    for (int j = lo + t; j < hi; j += 256) {
        int2 p = bbuf[j];
        int dloc = (p.x >> 17) & (NPB - 1);
        int r = atomicAdd(&deg[dloc], 1);
        edge2[lo + loff[dloc] + r] = make_int2(p.x & 0x1FFFF, p.y);
    }
}

// ---------------- MFMA fused 3-GEMM ----------------
// a(bf16) = hW1+b1 ; d = hW3+b3 - (hW2)*wsum
// block = 256 thr (4 waves), 64 nodes. wave w owns output coltile w (16 feats),
// all 3 matrices, 4 M-tiles of 16 nodes. mfma_f32_16x16x32_bf16:
//   A: lane row = l&15, k = (l>>4)*8 + j  (j=0..7)
//   B: lane col = l&15, k = (l>>4)*8 + j
//   D: col = l&15, row = (l>>4)*4 + r
__global__ __launch_bounds__(256) void k_gemm3(
    const float* __restrict__ h,
    const float* __restrict__ W1, const float* __restrict__ b1,
    const float* __restrict__ W2,
    const float* __restrict__ W3, const float* __restrict__ b3,
    const float* __restrict__ wsum,
    unsigned short* __restrict__ a_out, float* __restrict__ d_out_) {
    int wave = threadIdx.x >> 6;   // coltile 0..3
    int lane = threadIdx.x & 63;
    int row = lane & 15;
    int kg = lane >> 4;            // k-group 0..3
    int base = blockIdx.x * 64;
    int col = wave * 16 + row;     // output feature for B-load & epilogue

    // ---- load B fragments (once): Bf[mat][khalf] ----
    bf16x8 Bf[3][2];
    const float* Ws[3] = {W1, W2, W3};
#pragma unroll
    for (int m = 0; m < 3; ++m)
#pragma unroll
        for (int hf = 0; hf < 2; ++hf) {
            union { bf16x8 v; unsigned short u[8]; } fr;
#pragma unroll
            for (int j = 0; j < 8; ++j) {
                int k = hf * 32 + kg * 8 + j;
                fr.u[j] = f2bf(Ws[m][k * HDIM + col]);
            }
            Bf[m][hf] = fr.v;
        }

    float bias1 = b1[col];
    float bias3 = b3[col];

    f32x4 acc[3][4];
#pragma unroll
    for (int m = 0; m < 3; ++m)
#pragma unroll
        for (int t = 0; t < 4; ++t) acc[m][t] = (f32x4){0.f, 0.f, 0.f, 0.f};

#pragma unroll
    for (int t = 0; t < 4; ++t) {
        int n = base + t * 16 + row;
        union { bf16x8 v; unsigned short u[8]; } a0, a1;
        if (n < N_NODES) {
            const float* hr = h + (size_t)n * HDIM;
            float4 p0 = *(const float4*)(hr + kg * 8);
            float4 p1 = *(const float4*)(hr + kg * 8 + 4);
            float4 q0 = *(const float4*)(hr + 32 + kg * 8);
            float4 q1 = *(const float4*)(hr + 32 + kg * 8 + 4);
            a0.u[0] = f2bf(p0.x); a0.u[1] = f2bf(p0.y); a0.u[2] = f2bf(p0.z); a0.u[3] = f2bf(p0.w);
            a0.u[4] = f2bf(p1.x); a0.u[5] = f2bf(p1.y); a0.u[6] = f2bf(p1.z); a0.u[7] = f2bf(p1.w);
            a1.u[0] = f2bf(q0.x); a1.u[1] = f2bf(q0.y); a1.u[2] = f2bf(q0.z); a1.u[3] = f2bf(q0.w);
            a1.u[4] = f2bf(q1.x); a1.u[5] = f2bf(q1.y); a1.u[6] = f2bf(q1.z); a1.u[7] = f2bf(q1.w);
        } else {
#pragma unroll
            for (int j = 0; j < 8; ++j) { a0.u[j] = 0; a1.u[j] = 0; }
        }
#pragma unroll
        for (int m = 0; m < 3; ++m) {
            acc[m][t] = __builtin_amdgcn_mfma_f32_16x16x32_bf16(a0.v, Bf[m][0], acc[m][t], 0, 0, 0);
            acc[m][t] = __builtin_amdgcn_mfma_f32_16x16x32_bf16(a1.v, Bf[m][1], acc[m][t], 0, 0, 0);
        }
    }

    // ---- epilogue ----
#pragma unroll
    for (int t = 0; t < 4; ++t) {
#pragma unroll
        for (int r = 0; r < 4; ++r) {
            int n = base + t * 16 + kg * 4 + r;
            if (n >= N_NODES) continue;
            float ws = wsum[n];
            float av = acc[0][t][r] + bias1;
            float dv = acc[2][t][r] + bias3 - acc[1][t][r] * ws;
            a_out[(size_t)n * HDIM + col] = f2bf(av);
            d_out_[(size_t)n * HDIM + col] = dv;
        }
    }
}

// ---------------- CSR aggregate + relu: h = relu(sum_j a[src_j]*w_j + d) ----------------
// Quarter-wave layout: 4 edge slots x 16 lanes, bf16x4 per lane (8B).
__global__ __launch_bounds__(256) void k_agg(const int2* __restrict__ edge2,
                                             const int* __restrict__ off,
                                             const unsigned short* __restrict__ a,
                                             const float* __restrict__ dbuf,
                                             float* __restrict__ h) {
    int wid = threadIdx.x >> 6;
    int lane = threadIdx.x & 63;
    int slot = lane >> 4;        // 0..3
    int fq = lane & 15;          // feature quad: floats [fq*4, fq*4+4)
    int n = blockIdx.x * 4 + wid;
    if (n >= N_NODES) return;
    int lo = off[n], hi = off[n + 1];

    float4 acc0 = {0.f, 0.f, 0.f, 0.f};
    float4 acc1 = {0.f, 0.f, 0.f, 0.f};
    int j = lo + slot;
    for (; j + 4 < hi; j += 8) {
        int2 p0 = edge2[j];
        int2 p1 = edge2[j + 4];
        float w0 = __int_as_float(p0.y);
        float w1 = __int_as_float(p1.y);
        ushort4 u0 = *(const ushort4*)(a + (size_t)p0.x * HDIM + fq * 4);
        ushort4 u1 = *(const ushort4*)(a + (size_t)p1.x * HDIM + fq * 4);
        acc0.x += bf2f(u0.x) * w0; acc0.y += bf2f(u0.y) * w0;
        acc0.z += bf2f(u0.z) * w0; acc0.w += bf2f(u0.w) * w0;
        acc1.x += bf2f(u1.x) * w1; acc1.y += bf2f(u1.y) * w1;
        acc1.z += bf2f(u1.z) * w1; acc1.w += bf2f(u1.w) * w1;
    }
    if (j < hi) {
        int2 p0 = edge2[j];
        float w0 = __int_as_float(p0.y);
        ushort4 u0 = *(const ushort4*)(a + (size_t)p0.x * HDIM + fq * 4);
        acc0.x += bf2f(u0.x) * w0; acc0.y += bf2f(u0.y) * w0;
        acc0.z += bf2f(u0.z) * w0; acc0.w += bf2f(u0.w) * w0;
    }
    acc0.x += acc1.x; acc0.y += acc1.y; acc0.z += acc1.z; acc0.w += acc1.w;

    acc0.x += __shfl_xor(acc0.x, 16); acc0.y += __shfl_xor(acc0.y, 16);
    acc0.z += __shfl_xor(acc0.z, 16); acc0.w += __shfl_xor(acc0.w, 16);
    acc0.x += __shfl_xor(acc0.x, 32); acc0.y += __shfl_xor(acc0.y, 32);
    acc0.z += __shfl_xor(acc0.z, 32); acc0.w += __shfl_xor(acc0.w, 32);

    if (slot == 0) {
        float4 dv = *(const float4*)(dbuf + (size_t)n * HDIM + fq * 4);
        float4 o;
        o.x = fmaxf(acc0.x + dv.x, 0.f);
        o.y = fmaxf(acc0.y + dv.y, 0.f);
        o.z = fmaxf(acc0.z + dv.z, 0.f);
        o.w = fmaxf(acc0.w + dv.w, 0.f);
        *(float4*)(h + (size_t)n * HDIM + fq * 4) = o;
    }
}

// ---------------- graph boundaries from sorted batch ----------------
__global__ void k_bounds(const int* __restrict__ batch, int* __restrict__ goff) {
    int n = blockIdx.x * blockDim.x + threadIdx.x;
    if (n >= N_NODES) return;
    int b = batch[n];
    int bp = (n == 0) ? -1 : batch[n - 1];
    for (int g = bp + 1; g <= b; ++g) goff[g] = n;
    if (n == N_NODES - 1) {
        for (int g = b + 1; g <= G_GRAPHS; ++g) goff[g] = N_NODES;
    }
}

// ---------------- mean pool: one wave per graph ----------------
__global__ __launch_bounds__(64) void k_pool(const float* __restrict__ h,
                                             const int* __restrict__ goff,
                                             float* __restrict__ gx) {
    int g = blockIdx.x;
    int lane = threadIdx.x;
    int lo = goff[g], hi = goff[g + 1];
    float acc = 0.f;
    for (int n = lo; n < hi; ++n) acc += h[(size_t)n * HDIM + lane];
    float cnt = (float)(hi - lo);
    gx[g * HDIM + lane] = acc / fmaxf(cnt, 1.f);
}

// ---------------- head: out = relu(gx@W1+b1)@W2+b2 ----------------
__global__ __launch_bounds__(128) void k_head(const float* __restrict__ gx,
                                              const float* __restrict__ W1,
                                              const float* __restrict__ b1,
                                              const float* __restrict__ W2,
                                              const float* __restrict__ b2,
                                              float* __restrict__ out) {
    int g = blockIdx.x;
    __shared__ float sx[HDIM];
    __shared__ float sy[2 * HDIM];
    int tid = threadIdx.x;
    if (tid < HDIM) sx[tid] = gx[g * HDIM + tid];
    __syncthreads();
    float acc = b1[tid];
    for (int k = 0; k < HDIM; ++k) acc += sx[k] * W1[k * 2 * HDIM + tid];
    sy[tid] = fmaxf(acc, 0.f);
    __syncthreads();
    if (tid < C_CLS) {
        float o = b2[tid];
        for (int k = 0; k < 2 * HDIM; ++k) o += sy[k] * W2[k * C_CLS + tid];
        out[g * C_CLS + tid] = o;
    }
}

extern "C" void kernel_launch(void* const* d_in, const int* in_sizes, int n_in,
                              void* d_out, int out_size, void* d_ws, size_t ws_size,
                              hipStream_t stream) {
    const float* x      = (const float*)d_in[0];
    const int*   ei     = (const int*)d_in[1];
    const float* eattr  = (const float*)d_in[2];
    const int*   batch  = (const int*)d_in[3];
    const float* w_emb  = (const float*)d_in[4];
    const float* b_emb  = (const float*)d_in[5];
    const float* lin1_w = (const float*)d_in[6];
    const float* lin1_b = (const float*)d_in[7];
    const float* lin2_w = (const float*)d_in[8];
    const float* lin3_w = (const float*)d_in[9];
    const float* lin3_b = (const float*)d_in[10];
    const float* mlp_w1 = (const float*)d_in[11];
    const float* mlp_b1 = (const float*)d_in[12];
    const float* mlp_w2 = (const float*)d_in[13];
    const float* mlp_b2 = (const float*)d_in[14];
    float* out = (float*)d_out;

    const int* src = ei;
    const int* dst = ei + N_EDGES;

    const size_t NH = (size_t)N_NODES * HDIM;
    float* fws = (float*)d_ws;
    float* h    = fws;                 // NH floats
    float* dbuf = h + NH;              // NH floats
    float* wsum = dbuf + NH;           // N
    float* gx   = wsum + N_NODES;      // G*H
    unsigned short* abf = (unsigned short*)(gx + (size_t)G_GRAPHS * HDIM);  // NH bf16
    int2* edge2 = (int2*)(abf + NH);   // E (8B each)
    int2* bbuf  = edge2 + N_EDGES;     // E
    int* off    = (int*)(bbuf + N_EDGES);  // N+1
    int* bcnt   = off + N_NODES + 1;   // NB (zeroed)
    int* bcur   = bcnt + NB;           // NB
    int* boff   = bcur + NB;           // NB+1
    int* goff   = boff + NB + 1;       // G+1

    hipMemsetAsync(bcnt, 0, NB * sizeof(int), stream);

    int nh_blocks = (N_NODES * HDIM + 255) / 256;
    int n_blocks = (N_NODES + 255) / 256;

    k_emb<<<nh_blocks, 256, 0, stream>>>(x, w_emb, b_emb, h);
    k_hist<<<512, 256, 0, stream>>>(dst, bcnt);
    k_boff<<<1, 256, 0, stream>>>(bcnt, boff, bcur);
    k_bucket<<<CBLK, 1024, 0, stream>>>(src, dst, eattr, bcur, bbuf);
    k_csr<<<NB, 256, 0, stream>>>(bbuf, boff, off, wsum, edge2);
    k_bounds<<<n_blocks, 256, 0, stream>>>(batch, goff);

    int gemm_blocks = (N_NODES + 63) / 64;
    int agg_blocks = (N_NODES + 3) / 4;

    for (int l = 0; l < 2; ++l) {
        const float* W1 = lin1_w + l * HDIM * HDIM;
        const float* B1 = lin1_b + l * HDIM;
        const float* W2 = lin2_w + l * HDIM * HDIM;
        const float* W3 = lin3_w + l * HDIM * HDIM;
        const float* B3 = lin3_b + l * HDIM;
        k_gemm3<<<gemm_blocks, 256, 0, stream>>>(h, W1, B1, W2, W3, B3, wsum, abf, dbuf);
        k_agg<<<agg_blocks, 256, 0, stream>>>(edge2, off, abf, dbuf, h);
    }

    k_pool<<<G_GRAPHS, 64, 0, stream>>>(h, goff, gx);
    k_head<<<G_GRAPHS, 128, 0, stream>>>(gx, mlp_w1, mlp_b1, mlp_w2, mlp_b2, out);
}

// Round 7
// 262.967 us; speedup vs baseline: 4.0243x; 1.1242x over previous
//
#include <hip/hip_runtime.h>

#define N_NODES 100000
#define N_EDGES 1600000
#define F_INPUT 4
#define HDIM 64
#define G_GRAPHS 1000
#define C_CLS 3

#define NPB 256          // nodes per bucket (power of 2)
#define BSHIFT 8
#define NB 391           // ceil(N_NODES / NPB)
#define CBLK 391         // ceil(N_EDGES / 4096)
#define CSR_CAP 6144     // max edges per bucket staged in LDS (mean 4096, +32 sigma)
#define EMB_BLOCKS 25000 // ceil(N*H / 256)
#define HIST_BLOCKS 512

typedef __attribute__((ext_vector_type(8))) short bf16x8;
typedef __attribute__((ext_vector_type(4))) float f32x4;

__device__ __forceinline__ unsigned short f2bf(float f) {
    unsigned u = __float_as_uint(f);
    unsigned r = (u + 0x7FFF + ((u >> 16) & 1)) >> 16;  // round-to-nearest-even
    return (unsigned short)r;
}
__device__ __forceinline__ float bflo(unsigned u) {
    return __uint_as_float(u << 16);
}
__device__ __forceinline__ float bfhi(unsigned u) {
    return __uint_as_float(u & 0xFFFF0000u);
}

// ---------------- fused: embedding + bucket histogram ----------------
__global__ __launch_bounds__(256) void k_emb_hist(
    const float* __restrict__ x, const float* __restrict__ w, const float* __restrict__ b,
    float* __restrict__ h, const int* __restrict__ dst, int* __restrict__ bcnt) {
    __shared__ int s[NB];
    if (blockIdx.x < EMB_BLOCKS) {
        int t = blockIdx.x * 256 + threadIdx.x;
        if (t >= N_NODES * HDIM) return;
        int n = t >> 6, f = t & 63;
        const float* xr = x + n * F_INPUT;
        float acc = b[f];
#pragma unroll
        for (int k = 0; k < F_INPUT; ++k) acc += xr[k] * w[k * HDIM + f];
        h[t] = acc;
    } else {
        int bb = blockIdx.x - EMB_BLOCKS;
        for (int i = threadIdx.x; i < NB; i += 256) s[i] = 0;
        __syncthreads();
        for (int e = bb * 256 + threadIdx.x; e < N_EDGES; e += HIST_BLOCKS * 256)
            atomicAdd(&s[dst[e] >> BSHIFT], 1);
        __syncthreads();
        for (int i = threadIdx.x; i < NB; i += 256)
            if (s[i]) atomicAdd(&bcnt[i], s[i]);
    }
}

// ---------------- fused: bucket-offset scan + graph boundaries ----------------
__global__ __launch_bounds__(512) void k_boff_bounds(
    const int* __restrict__ bcnt, int* __restrict__ boff, int* __restrict__ bcur,
    const int* __restrict__ batch, int* __restrict__ goff) {
    if (blockIdx.x == 0) {
        __shared__ int s[512];
        int t = threadIdx.x;
        int v = (t < NB) ? bcnt[t] : 0;
        s[t] = v;
        __syncthreads();
        for (int d = 1; d < 512; d <<= 1) {
            int x2 = (t >= d) ? s[t - d] : 0;
            __syncthreads();
            s[t] += x2;
            __syncthreads();
        }
        int ex = s[t] - v;
        if (t < NB) { boff[t] = ex; bcur[t] = ex; }
        if (t == 0) boff[NB] = N_EDGES;
    } else {
        int n = (blockIdx.x - 1) * 512 + threadIdx.x;
        if (n >= N_NODES) return;
        int bv = batch[n];
        int bp = (n == 0) ? -1 : batch[n - 1];
        for (int g = bp + 1; g <= bv; ++g) goff[g] = n;
        if (n == N_NODES - 1) {
            for (int g = bv + 1; g <= G_GRAPHS; ++g) goff[g] = N_NODES;
        }
    }
}

// ---------------- scatter edges into buckets (packed 8B records) ----------------
// record: x = src | (dloc << 17) ; y = bits of w
__global__ __launch_bounds__(1024) void k_bucket(const int* __restrict__ src,
                                                 const int* __restrict__ dst,
                                                 const float* __restrict__ attr,
                                                 int* __restrict__ bcur,
                                                 int2* __restrict__ bbuf) {
    __shared__ int cnt[NB];
    __shared__ int base[NB];
    for (int i = threadIdx.x; i < NB; i += 1024) cnt[i] = 0;
    __syncthreads();
    int e0 = blockIdx.x * 4096;
    int myb[4], myrank[4];
    int2 mypack[4];
#pragma unroll
    for (int k = 0; k < 4; ++k) {
        int e = e0 + k * 1024 + threadIdx.x;
        if (e < N_EDGES) {
            int d = dst[e];
            int b = d >> BSHIFT;
            myb[k] = b;
            myrank[k] = atomicAdd(&cnt[b], 1);
            mypack[k].x = src[e] | ((d & (NPB - 1)) << 17);
            mypack[k].y = __float_as_int(attr[e]);
        } else
            myb[k] = -1;
    }
    __syncthreads();
    for (int i = threadIdx.x; i < NB; i += 1024)
        base[i] = cnt[i] ? atomicAdd(&bcur[i], cnt[i]) : 0;
    __syncthreads();
#pragma unroll
    for (int k = 0; k < 4; ++k)
        if (myb[k] >= 0) bbuf[base[myb[k]] + myrank[k]] = mypack[k];
}

// ---------------- per-bucket CSR finalize (single pass, LDS-staged) ----------------
__global__ __launch_bounds__(256) void k_csr(const int2* __restrict__ bbuf,
                                             const int* __restrict__ boff,
                                             int* __restrict__ off,
                                             float* __restrict__ wsum,
                                             int2* __restrict__ edge2) {
    __shared__ int2 se[CSR_CAP];   // 48 KB
    __shared__ int deg[NPB];
    __shared__ float wsm[NPB];
    __shared__ int loff[NPB];
    __shared__ int sct[256];
    int b = blockIdx.x;
    int lo = boff[b];
    int cnt = boff[b + 1] - lo;
    if (cnt > CSR_CAP) cnt = CSR_CAP;   // statistically impossible; safety clamp
    int t = threadIdx.x;
    deg[t] = 0;
    wsm[t] = 0.f;
    for (int i = t; i < cnt; i += 256) se[i] = bbuf[lo + i];
    __syncthreads();
    for (int i = t; i < cnt; i += 256) {
        int2 p = se[i];
        int dloc = (p.x >> 17) & (NPB - 1);
        atomicAdd(&deg[dloc], 1);
        atomicAdd(&wsm[dloc], __int_as_float(p.y));
    }
    __syncthreads();
    // exclusive scan of deg[256]
    int v = deg[t];
    sct[t] = v;
    __syncthreads();
    for (int d = 1; d < 256; d <<= 1) {
        int x2 = (t >= d) ? sct[t - d] : 0;
        __syncthreads();
        sct[t] += x2;
        __syncthreads();
    }
    int ex = sct[t] - v;
    loff[t] = ex;
    __syncthreads();
    int n = b * NPB + t;
    if (n < N_NODES) { off[n] = lo + ex; wsum[n] = wsm[t]; }
    if (b == NB - 1 && t == 0) off[N_NODES] = N_EDGES;
    deg[t] = 0;  // reuse as cursor
    __syncthreads();
    for (int i = t; i < cnt; i += 256) {
        int2 p = se[i];
        int dloc = (p.x >> 17) & (NPB - 1);
        int r = atomicAdd(&deg[dloc], 1);
        edge2[lo + loff[dloc] + r] = make_int2(p.x & 0x1FFFF, p.y);
    }
}

// ---------------- MFMA fused 3-GEMM ----------------
// a(bf16) = hW1+b1 ; d = hW3+b3 - (hW2)*wsum
__global__ __launch_bounds__(256) void k_gemm3(
    const float* __restrict__ h,
    const float* __restrict__ W1, const float* __restrict__ b1,
    const float* __restrict__ W2,
    const float* __restrict__ W3, const float* __restrict__ b3,
    const float* __restrict__ wsum,
    unsigned short* __restrict__ a_out, float* __restrict__ d_out_) {
    int wave = threadIdx.x >> 6;   // coltile 0..3
    int lane = threadIdx.x & 63;
    int row = lane & 15;
    int kg = lane >> 4;            // k-group 0..3
    int base = blockIdx.x * 64;
    int col = wave * 16 + row;     // output feature

    bf16x8 Bf[3][2];
    const float* Ws[3] = {W1, W2, W3};
#pragma unroll
    for (int m = 0; m < 3; ++m)
#pragma unroll
        for (int hf = 0; hf < 2; ++hf) {
            union { bf16x8 v; unsigned short u[8]; } fr;
#pragma unroll
            for (int j = 0; j < 8; ++j) {
                int k = hf * 32 + kg * 8 + j;
                fr.u[j] = f2bf(Ws[m][k * HDIM + col]);
            }
            Bf[m][hf] = fr.v;
        }

    float bias1 = b1[col];
    float bias3 = b3[col];

    f32x4 acc[3][4];
#pragma unroll
    for (int m = 0; m < 3; ++m)
#pragma unroll
        for (int t = 0; t < 4; ++t) acc[m][t] = (f32x4){0.f, 0.f, 0.f, 0.f};

#pragma unroll
    for (int t = 0; t < 4; ++t) {
        int n = base + t * 16 + row;
        union { bf16x8 v; unsigned short u[8]; } a0, a1;
        if (n < N_NODES) {
            const float* hr = h + (size_t)n * HDIM;
            float4 p0 = *(const float4*)(hr + kg * 8);
            float4 p1 = *(const float4*)(hr + kg * 8 + 4);
            float4 q0 = *(const float4*)(hr + 32 + kg * 8);
            float4 q1 = *(const float4*)(hr + 32 + kg * 8 + 4);
            a0.u[0] = f2bf(p0.x); a0.u[1] = f2bf(p0.y); a0.u[2] = f2bf(p0.z); a0.u[3] = f2bf(p0.w);
            a0.u[4] = f2bf(p1.x); a0.u[5] = f2bf(p1.y); a0.u[6] = f2bf(p1.z); a0.u[7] = f2bf(p1.w);
            a1.u[0] = f2bf(q0.x); a1.u[1] = f2bf(q0.y); a1.u[2] = f2bf(q0.z); a1.u[3] = f2bf(q0.w);
            a1.u[4] = f2bf(q1.x); a1.u[5] = f2bf(q1.y); a1.u[6] = f2bf(q1.z); a1.u[7] = f2bf(q1.w);
        } else {
#pragma unroll
            for (int j = 0; j < 8; ++j) { a0.u[j] = 0; a1.u[j] = 0; }
        }
#pragma unroll
        for (int m = 0; m < 3; ++m) {
            acc[m][t] = __builtin_amdgcn_mfma_f32_16x16x32_bf16(a0.v, Bf[m][0], acc[m][t], 0, 0, 0);
            acc[m][t] = __builtin_amdgcn_mfma_f32_16x16x32_bf16(a1.v, Bf[m][1], acc[m][t], 0, 0, 0);
        }
    }

#pragma unroll
    for (int t = 0; t < 4; ++t) {
#pragma unroll
        for (int r = 0; r < 4; ++r) {
            int n = base + t * 16 + kg * 4 + r;
            if (n >= N_NODES) continue;
            float ws = wsum[n];
            float av = acc[0][t][r] + bias1;
            float dv = acc[2][t][r] + bias3 - acc[1][t][r] * ws;
            a_out[(size_t)n * HDIM + col] = f2bf(av);
            d_out_[(size_t)n * HDIM + col] = dv;
        }
    }
}

// ---------------- CSR aggregate + relu: h = relu(sum_j a[src_j]*w_j + d) ----------------
// 8 slots x 8 lanes; each lane gathers bf16x8 (16B), unroll x2 -> 16 edges/iter.
__global__ __launch_bounds__(256) void k_agg(const int2* __restrict__ edge2,
                                             const int* __restrict__ off,
                                             const unsigned short* __restrict__ a,
                                             const float* __restrict__ dbuf,
                                             float* __restrict__ h) {
    int wid = threadIdx.x >> 6;
    int lane = threadIdx.x & 63;
    int slot = lane >> 3;        // 0..7
    int fo = lane & 7;           // feature octet: feats [fo*8, fo*8+8)
    int n = blockIdx.x * 4 + wid;
    if (n >= N_NODES) return;
    int lo = off[n], hi = off[n + 1];

    float acc[8];
#pragma unroll
    for (int q = 0; q < 8; ++q) acc[q] = 0.f;

    for (int j0 = lo; j0 < hi; j0 += 16) {
        int j1 = j0 + slot;
        int j2 = j0 + 8 + slot;
        if (j1 < hi) {
            int2 p = edge2[j1];
            float w = __int_as_float(p.y);
            uint4 u = *(const uint4*)(a + (size_t)p.x * HDIM + fo * 8);
            acc[0] += bflo(u.x) * w; acc[1] += bfhi(u.x) * w;
            acc[2] += bflo(u.y) * w; acc[3] += bfhi(u.y) * w;
            acc[4] += bflo(u.z) * w; acc[5] += bfhi(u.z) * w;
            acc[6] += bflo(u.w) * w; acc[7] += bfhi(u.w) * w;
        }
        if (j2 < hi) {
            int2 p = edge2[j2];
            float w = __int_as_float(p.y);
            uint4 u = *(const uint4*)(a + (size_t)p.x * HDIM + fo * 8);
            acc[0] += bflo(u.x) * w; acc[1] += bfhi(u.x) * w;
            acc[2] += bflo(u.y) * w; acc[3] += bfhi(u.y) * w;
            acc[4] += bflo(u.z) * w; acc[5] += bfhi(u.z) * w;
            acc[6] += bflo(u.w) * w; acc[7] += bfhi(u.w) * w;
        }
    }

    // reduce across the 8 slots (lane bits 3,4,5)
#pragma unroll
    for (int m = 8; m <= 32; m <<= 1) {
#pragma unroll
        for (int q = 0; q < 8; ++q) acc[q] += __shfl_xor(acc[q], m);
    }

    if (slot == 0) {
        size_t o = (size_t)n * HDIM + fo * 8;
        float4 d0 = *(const float4*)(dbuf + o);
        float4 d1 = *(const float4*)(dbuf + o + 4);
        float4 o0, o1;
        o0.x = fmaxf(acc[0] + d0.x, 0.f); o0.y = fmaxf(acc[1] + d0.y, 0.f);
        o0.z = fmaxf(acc[2] + d0.z, 0.f); o0.w = fmaxf(acc[3] + d0.w, 0.f);
        o1.x = fmaxf(acc[4] + d1.x, 0.f); o1.y = fmaxf(acc[5] + d1.y, 0.f);
        o1.z = fmaxf(acc[6] + d1.z, 0.f); o1.w = fmaxf(acc[7] + d1.w, 0.f);
        *(float4*)(h + o) = o0;
        *(float4*)(h + o + 4) = o1;
    }
}

// ---------------- fused mean pool + MLP head: one block per graph ----------------
__global__ __launch_bounds__(128) void k_poolhead(const float* __restrict__ h,
                                                  const int* __restrict__ goff,
                                                  const float* __restrict__ W1,
                                                  const float* __restrict__ b1,
                                                  const float* __restrict__ W2,
                                                  const float* __restrict__ b2,
                                                  float* __restrict__ out) {
    int g = blockIdx.x;
    __shared__ float part[128];
    __shared__ float sx[HDIM];
    __shared__ float sy[2 * HDIM];
    int t = threadIdx.x;
    int lo = goff[g], hi = goff[g + 1];
    int f = t & 63, half = t >> 6;
    float acc = 0.f;
    for (int n = lo + half; n < hi; n += 2) acc += h[(size_t)n * HDIM + f];
    part[t] = acc;
    __syncthreads();
    if (t < HDIM) sx[t] = (part[t] + part[t + 64]) / fmaxf((float)(hi - lo), 1.f);
    __syncthreads();
    float a1 = b1[t];
    for (int k = 0; k < HDIM; ++k) a1 += sx[k] * W1[k * 2 * HDIM + t];
    sy[t] = fmaxf(a1, 0.f);
    __syncthreads();
    if (t < C_CLS) {
        float o = b2[t];
        for (int k = 0; k < 2 * HDIM; ++k) o += sy[k] * W2[k * C_CLS + t];
        out[g * C_CLS + t] = o;
    }
}

extern "C" void kernel_launch(void* const* d_in, const int* in_sizes, int n_in,
                              void* d_out, int out_size, void* d_ws, size_t ws_size,
                              hipStream_t stream) {
    const float* x      = (const float*)d_in[0];
    const int*   ei     = (const int*)d_in[1];
    const float* eattr  = (const float*)d_in[2];
    const int*   batch  = (const int*)d_in[3];
    const float* w_emb  = (const float*)d_in[4];
    const float* b_emb  = (const float*)d_in[5];
    const float* lin1_w = (const float*)d_in[6];
    const float* lin1_b = (const float*)d_in[7];
    const float* lin2_w = (const float*)d_in[8];
    const float* lin3_w = (const float*)d_in[9];
    const float* lin3_b = (const float*)d_in[10];
    const float* mlp_w1 = (const float*)d_in[11];
    const float* mlp_b1 = (const float*)d_in[12];
    const float* mlp_w2 = (const float*)d_in[13];
    const float* mlp_b2 = (const float*)d_in[14];
    float* out = (float*)d_out;

    const int* src = ei;
    const int* dst = ei + N_EDGES;

    const size_t NH = (size_t)N_NODES * HDIM;
    float* fws = (float*)d_ws;
    float* h    = fws;                 // NH floats
    float* dbuf = h + NH;              // NH floats
    float* wsum = dbuf + NH;           // N
    unsigned short* abf = (unsigned short*)(wsum + N_NODES);  // NH bf16
    int2* edge2 = (int2*)(abf + NH);   // E (8B each)
    int2* bbuf  = edge2 + N_EDGES;     // E
    int* off    = (int*)(bbuf + N_EDGES);  // N+1
    int* bcnt   = off + N_NODES + 1;   // NB (zeroed)
    int* bcur   = bcnt + NB;           // NB
    int* boff   = bcur + NB;           // NB+1
    int* goff   = boff + NB + 1;       // G+1

    hipMemsetAsync(bcnt, 0, NB * sizeof(int), stream);

    k_emb_hist<<<EMB_BLOCKS + HIST_BLOCKS, 256, 0, stream>>>(x, w_emb, b_emb, h, dst, bcnt);
    k_boff_bounds<<<1 + (N_NODES + 511) / 512, 512, 0, stream>>>(bcnt, boff, bcur, batch, goff);
    k_bucket<<<CBLK, 1024, 0, stream>>>(src, dst, eattr, bcur, bbuf);
    k_csr<<<NB, 256, 0, stream>>>(bbuf, boff, off, wsum, edge2);

    int gemm_blocks = (N_NODES + 63) / 64;
    int agg_blocks = (N_NODES + 3) / 4;

    for (int l = 0; l < 2; ++l) {
        const float* W1 = lin1_w + l * HDIM * HDIM;
        const float* B1 = lin1_b + l * HDIM;
        const float* W2 = lin2_w + l * HDIM * HDIM;
        const float* W3 = lin3_w + l * HDIM * HDIM;
        const float* B3 = lin3_b + l * HDIM;
        k_gemm3<<<gemm_blocks, 256, 0, stream>>>(h, W1, B1, W2, W3, B3, wsum, abf, dbuf);
        k_agg<<<agg_blocks, 256, 0, stream>>>(edge2, off, abf, dbuf, h);
    }

    k_poolhead<<<G_GRAPHS, 128, 0, stream>>>(h, goff, mlp_w1, mlp_b1, mlp_w2, mlp_b2, out);
}

// Round 8
// 240.221 us; speedup vs baseline: 4.4053x; 1.0947x over previous
//
#include <hip/hip_runtime.h>

#define N_NODES 100000
#define N_EDGES 1600000
#define F_INPUT 4
#define HDIM 64
#define G_GRAPHS 1000
#define C_CLS 3

#define NPB 256          // nodes per bucket (power of 2)
#define BSHIFT 8
#define NB 391           // ceil(N_NODES / NPB)
#define CBLK 196         // ceil(N_EDGES / 8192)
#define CSR_CAP 6144     // max edges per bucket staged in LDS
#define EMB_BLOCKS 6250  // N*16 / 256 (4 feats per thread)
#define HIST_BLOCKS 512

typedef __attribute__((ext_vector_type(8))) short bf16x8;
typedef __attribute__((ext_vector_type(4))) float f32x4;

__device__ __forceinline__ unsigned short f2bf(float f) {
    unsigned u = __float_as_uint(f);
    unsigned r = (u + 0x7FFF + ((u >> 16) & 1)) >> 16;  // round-to-nearest-even
    return (unsigned short)r;
}
__device__ __forceinline__ float bflo(unsigned u) {
    return __uint_as_float(u << 16);
}
__device__ __forceinline__ float bfhi(unsigned u) {
    return __uint_as_float(u & 0xFFFF0000u);
}
__device__ __forceinline__ float bf1(unsigned short s) {
    return __uint_as_float(((unsigned)s) << 16);
}

// ---------------- fused: embedding (bf16 out) + bucket histogram ----------------
__global__ __launch_bounds__(256) void k_emb_hist(
    const float* __restrict__ x, const float* __restrict__ w, const float* __restrict__ b,
    unsigned short* __restrict__ h, const int* __restrict__ dst, int* __restrict__ bcnt) {
    __shared__ int s[NB];
    if (blockIdx.x < EMB_BLOCKS) {
        int t = blockIdx.x * 256 + threadIdx.x;   // [0, N*16)
        int n = t >> 4, f0 = (t & 15) * 4;
        const float* xr = x + n * F_INPUT;
        float x0 = xr[0], x1 = xr[1], x2 = xr[2], x3 = xr[3];
        ushort4 o;
        {
            float a0 = b[f0+0] + x0*w[0*HDIM+f0+0] + x1*w[1*HDIM+f0+0] + x2*w[2*HDIM+f0+0] + x3*w[3*HDIM+f0+0];
            float a1 = b[f0+1] + x0*w[0*HDIM+f0+1] + x1*w[1*HDIM+f0+1] + x2*w[2*HDIM+f0+1] + x3*w[3*HDIM+f0+1];
            float a2 = b[f0+2] + x0*w[0*HDIM+f0+2] + x1*w[1*HDIM+f0+2] + x2*w[2*HDIM+f0+2] + x3*w[3*HDIM+f0+2];
            float a3 = b[f0+3] + x0*w[0*HDIM+f0+3] + x1*w[1*HDIM+f0+3] + x2*w[2*HDIM+f0+3] + x3*w[3*HDIM+f0+3];
            o.x = f2bf(a0); o.y = f2bf(a1); o.z = f2bf(a2); o.w = f2bf(a3);
        }
        *(ushort4*)(h + (size_t)n * HDIM + f0) = o;
    } else {
        int bb = blockIdx.x - EMB_BLOCKS;
        for (int i = threadIdx.x; i < NB; i += 256) s[i] = 0;
        __syncthreads();
        for (int e = bb * 256 + threadIdx.x; e < N_EDGES; e += HIST_BLOCKS * 256)
            atomicAdd(&s[dst[e] >> BSHIFT], 1);
        __syncthreads();
        for (int i = threadIdx.x; i < NB; i += 256)
            if (s[i]) atomicAdd(&bcnt[i], s[i]);
    }
}

// ---------------- fused: bucket-offset scan + graph boundaries ----------------
__global__ __launch_bounds__(512) void k_boff_bounds(
    const int* __restrict__ bcnt, int* __restrict__ boff, int* __restrict__ bcur,
    const int* __restrict__ batch, int* __restrict__ goff) {
    if (blockIdx.x == 0) {
        __shared__ int s[512];
        int t = threadIdx.x;
        int v = (t < NB) ? bcnt[t] : 0;
        s[t] = v;
        __syncthreads();
        for (int d = 1; d < 512; d <<= 1) {
            int x2 = (t >= d) ? s[t - d] : 0;
            __syncthreads();
            s[t] += x2;
            __syncthreads();
        }
        int ex = s[t] - v;
        if (t < NB) { boff[t] = ex; bcur[t] = ex; }
        if (t == 0) boff[NB] = N_EDGES;
    } else {
        int n = (blockIdx.x - 1) * 512 + threadIdx.x;
        if (n >= N_NODES) return;
        int bv = batch[n];
        int bp = (n == 0) ? -1 : batch[n - 1];
        for (int g = bp + 1; g <= bv; ++g) goff[g] = n;
        if (n == N_NODES - 1) {
            for (int g = bv + 1; g <= G_GRAPHS; ++g) goff[g] = N_NODES;
        }
    }
}

// ---------------- scatter edges into buckets (packed 8B records) ----------------
// record: x = src | (dloc << 17) ; y = bits of w.  8 edges/thread for long runs.
__global__ __launch_bounds__(1024) void k_bucket(const int* __restrict__ src,
                                                 const int* __restrict__ dst,
                                                 const float* __restrict__ attr,
                                                 int* __restrict__ bcur,
                                                 int2* __restrict__ bbuf) {
    __shared__ int cnt[NB];
    __shared__ int base[NB];
    for (int i = threadIdx.x; i < NB; i += 1024) cnt[i] = 0;
    __syncthreads();
    int e0 = blockIdx.x * 8192;
    int myb[8], myrank[8];
    int2 mypack[8];
#pragma unroll
    for (int k = 0; k < 8; ++k) {
        int e = e0 + k * 1024 + threadIdx.x;
        if (e < N_EDGES) {
            int d = dst[e];
            int b = d >> BSHIFT;
            myb[k] = b;
            myrank[k] = atomicAdd(&cnt[b], 1);
            mypack[k].x = src[e] | ((d & (NPB - 1)) << 17);
            mypack[k].y = __float_as_int(attr[e]);
        } else
            myb[k] = -1;
    }
    __syncthreads();
    for (int i = threadIdx.x; i < NB; i += 1024)
        base[i] = cnt[i] ? atomicAdd(&bcur[i], cnt[i]) : 0;
    __syncthreads();
#pragma unroll
    for (int k = 0; k < 8; ++k)
        if (myb[k] >= 0) bbuf[base[myb[k]] + myrank[k]] = mypack[k];
}

// ---------------- per-bucket CSR finalize (single pass, LDS-staged) ----------------
__global__ __launch_bounds__(256) void k_csr(const int2* __restrict__ bbuf,
                                             const int* __restrict__ boff,
                                             int* __restrict__ off,
                                             float* __restrict__ wsum,
                                             int2* __restrict__ edge2) {
    __shared__ int2 se[CSR_CAP];   // 48 KB
    __shared__ int deg[NPB];
    __shared__ float wsm[NPB];
    __shared__ int loff[NPB];
    __shared__ int sct[256];
    int b = blockIdx.x;
    int lo = boff[b];
    int cnt = boff[b + 1] - lo;
    if (cnt > CSR_CAP) cnt = CSR_CAP;   // statistically impossible; safety clamp
    int t = threadIdx.x;
    deg[t] = 0;
    wsm[t] = 0.f;
    for (int i = t; i < cnt; i += 256) se[i] = bbuf[lo + i];
    __syncthreads();
    for (int i = t; i < cnt; i += 256) {
        int2 p = se[i];
        int dloc = (p.x >> 17) & (NPB - 1);
        atomicAdd(&deg[dloc], 1);
        atomicAdd(&wsm[dloc], __int_as_float(p.y));
    }
    __syncthreads();
    int v = deg[t];
    sct[t] = v;
    __syncthreads();
    for (int d = 1; d < 256; d <<= 1) {
        int x2 = (t >= d) ? sct[t - d] : 0;
        __syncthreads();
        sct[t] += x2;
        __syncthreads();
    }
    int ex = sct[t] - v;
    loff[t] = ex;
    __syncthreads();
    int n = b * NPB + t;
    if (n < N_NODES) { off[n] = lo + ex; wsum[n] = wsm[t]; }
    if (b == NB - 1 && t == 0) off[N_NODES] = N_EDGES;
    deg[t] = 0;  // reuse as cursor
    __syncthreads();
    for (int i = t; i < cnt; i += 256) {
        int2 p = se[i];
        int dloc = (p.x >> 17) & (NPB - 1);
        int r = atomicAdd(&deg[dloc], 1);
        edge2[lo + loff[dloc] + r] = make_int2(p.x & 0x1FFFF, p.y);
    }
}

// ---------------- MFMA fused 3-GEMM (h bf16 in; a bf16, d bf16 out) ----------------
__global__ __launch_bounds__(256) void k_gemm3(
    const unsigned short* __restrict__ h,
    const float* __restrict__ W1, const float* __restrict__ b1,
    const float* __restrict__ W2,
    const float* __restrict__ W3, const float* __restrict__ b3,
    const float* __restrict__ wsum,
    unsigned short* __restrict__ a_out, unsigned short* __restrict__ d_out_) {
    int wave = threadIdx.x >> 6;   // coltile 0..3
    int lane = threadIdx.x & 63;
    int row = lane & 15;
    int kg = lane >> 4;            // k-group 0..3
    int base = blockIdx.x * 64;
    int col = wave * 16 + row;     // output feature

    bf16x8 Bf[3][2];
    const float* Ws[3] = {W1, W2, W3};
#pragma unroll
    for (int m = 0; m < 3; ++m)
#pragma unroll
        for (int hf = 0; hf < 2; ++hf) {
            union { bf16x8 v; unsigned short u[8]; } fr;
#pragma unroll
            for (int j = 0; j < 8; ++j) {
                int k = hf * 32 + kg * 8 + j;
                fr.u[j] = f2bf(Ws[m][k * HDIM + col]);
            }
            Bf[m][hf] = fr.v;
        }

    float bias1 = b1[col];
    float bias3 = b3[col];

    f32x4 acc[3][4];
#pragma unroll
    for (int m = 0; m < 3; ++m)
#pragma unroll
        for (int t = 0; t < 4; ++t) acc[m][t] = (f32x4){0.f, 0.f, 0.f, 0.f};

#pragma unroll
    for (int t = 0; t < 4; ++t) {
        int n = base + t * 16 + row;
        bf16x8 a0, a1;
        if (n < N_NODES) {
            const unsigned short* hr = h + (size_t)n * HDIM;
            a0 = *(const bf16x8*)(hr + kg * 8);
            a1 = *(const bf16x8*)(hr + 32 + kg * 8);
        } else {
            a0 = (bf16x8){0,0,0,0,0,0,0,0};
            a1 = (bf16x8){0,0,0,0,0,0,0,0};
        }
#pragma unroll
        for (int m = 0; m < 3; ++m) {
            acc[m][t] = __builtin_amdgcn_mfma_f32_16x16x32_bf16(a0, Bf[m][0], acc[m][t], 0, 0, 0);
            acc[m][t] = __builtin_amdgcn_mfma_f32_16x16x32_bf16(a1, Bf[m][1], acc[m][t], 0, 0, 0);
        }
    }

#pragma unroll
    for (int t = 0; t < 4; ++t) {
#pragma unroll
        for (int r = 0; r < 4; ++r) {
            int n = base + t * 16 + kg * 4 + r;
            if (n >= N_NODES) continue;
            float ws = wsum[n];
            float av = acc[0][t][r] + bias1;
            float dv = acc[2][t][r] + bias3 - acc[1][t][r] * ws;
            a_out[(size_t)n * HDIM + col] = f2bf(av);
            d_out_[(size_t)n * HDIM + col] = f2bf(dv);
        }
    }
}

// ---------------- CSR aggregate + relu: h = relu(sum_j a[src_j]*w_j + d) ----------------
// 8 slots x 8 lanes; each lane gathers bf16x8 (16B), unroll x2.
__global__ __launch_bounds__(256) void k_agg(const int2* __restrict__ edge2,
                                             const int* __restrict__ off,
                                             const unsigned short* __restrict__ a,
                                             const unsigned short* __restrict__ dbuf,
                                             unsigned short* __restrict__ h) {
    int wid = threadIdx.x >> 6;
    int lane = threadIdx.x & 63;
    int slot = lane >> 3;        // 0..7
    int fo = lane & 7;           // feature octet: feats [fo*8, fo*8+8)
    int n = blockIdx.x * 4 + wid;
    if (n >= N_NODES) return;
    int lo = off[n], hi = off[n + 1];

    float acc[8];
#pragma unroll
    for (int q = 0; q < 8; ++q) acc[q] = 0.f;

    for (int j0 = lo; j0 < hi; j0 += 16) {
        int j1 = j0 + slot;
        int j2 = j0 + 8 + slot;
        if (j1 < hi) {
            int2 p = edge2[j1];
            float w = __int_as_float(p.y);
            uint4 u = *(const uint4*)(a + (size_t)p.x * HDIM + fo * 8);
            acc[0] += bflo(u.x) * w; acc[1] += bfhi(u.x) * w;
            acc[2] += bflo(u.y) * w; acc[3] += bfhi(u.y) * w;
            acc[4] += bflo(u.z) * w; acc[5] += bfhi(u.z) * w;
            acc[6] += bflo(u.w) * w; acc[7] += bfhi(u.w) * w;
        }
        if (j2 < hi) {
            int2 p = edge2[j2];
            float w = __int_as_float(p.y);
            uint4 u = *(const uint4*)(a + (size_t)p.x * HDIM + fo * 8);
            acc[0] += bflo(u.x) * w; acc[1] += bfhi(u.x) * w;
            acc[2] += bflo(u.y) * w; acc[3] += bfhi(u.y) * w;
            acc[4] += bflo(u.z) * w; acc[5] += bfhi(u.z) * w;
            acc[6] += bflo(u.w) * w; acc[7] += bfhi(u.w) * w;
        }
    }

#pragma unroll
    for (int m = 8; m <= 32; m <<= 1) {
#pragma unroll
        for (int q = 0; q < 8; ++q) acc[q] += __shfl_xor(acc[q], m);
    }

    if (slot == 0) {
        size_t o = (size_t)n * HDIM + fo * 8;
        uint4 dv = *(const uint4*)(dbuf + o);
        float dd[8] = {bflo(dv.x), bfhi(dv.x), bflo(dv.y), bfhi(dv.y),
                       bflo(dv.z), bfhi(dv.z), bflo(dv.w), bfhi(dv.w)};
        unsigned r[4];
#pragma unroll
        for (int q = 0; q < 4; ++q) {
            unsigned lo16 = f2bf(fmaxf(acc[2 * q] + dd[2 * q], 0.f));
            unsigned hi16 = f2bf(fmaxf(acc[2 * q + 1] + dd[2 * q + 1], 0.f));
            r[q] = lo16 | (hi16 << 16);
        }
        *(uint4*)(h + o) = make_uint4(r[0], r[1], r[2], r[3]);
    }
}

// ---------------- fused mean pool + MLP head: one block per graph ----------------
__global__ __launch_bounds__(128) void k_poolhead(const unsigned short* __restrict__ h,
                                                  const int* __restrict__ goff,
                                                  const float* __restrict__ W1,
                                                  const float* __restrict__ b1,
                                                  const float* __restrict__ W2,
                                                  const float* __restrict__ b2,
                                                  float* __restrict__ out) {
    int g = blockIdx.x;
    __shared__ float part[128];
    __shared__ float sx[HDIM];
    __shared__ float sy[2 * HDIM];
    int t = threadIdx.x;
    int lo = goff[g], hi = goff[g + 1];
    int f = t & 63, half = t >> 6;
    float acc = 0.f;
    for (int n = lo + half; n < hi; n += 2) acc += bf1(h[(size_t)n * HDIM + f]);
    part[t] = acc;
    __syncthreads();
    if (t < HDIM) sx[t] = (part[t] + part[t + 64]) / fmaxf((float)(hi - lo), 1.f);
    __syncthreads();
    float a1 = b1[t];
    for (int k = 0; k < HDIM; ++k) a1 += sx[k] * W1[k * 2 * HDIM + t];
    sy[t] = fmaxf(a1, 0.f);
    __syncthreads();
    if (t < C_CLS) {
        float o = b2[t];
        for (int k = 0; k < 2 * HDIM; ++k) o += sy[k] * W2[k * C_CLS + t];
        out[g * C_CLS + t] = o;
    }
}

extern "C" void kernel_launch(void* const* d_in, const int* in_sizes, int n_in,
                              void* d_out, int out_size, void* d_ws, size_t ws_size,
                              hipStream_t stream) {
    const float* x      = (const float*)d_in[0];
    const int*   ei     = (const int*)d_in[1];
    const float* eattr  = (const float*)d_in[2];
    const int*   batch  = (const int*)d_in[3];
    const float* w_emb  = (const float*)d_in[4];
    const float* b_emb  = (const float*)d_in[5];
    const float* lin1_w = (const float*)d_in[6];
    const float* lin1_b = (const float*)d_in[7];
    const float* lin2_w = (const float*)d_in[8];
    const float* lin3_w = (const float*)d_in[9];
    const float* lin3_b = (const float*)d_in[10];
    const float* mlp_w1 = (const float*)d_in[11];
    const float* mlp_b1 = (const float*)d_in[12];
    const float* mlp_w2 = (const float*)d_in[13];
    const float* mlp_b2 = (const float*)d_in[14];
    float* out = (float*)d_out;

    const int* src = ei;
    const int* dst = ei + N_EDGES;

    const size_t NH = (size_t)N_NODES * HDIM;
    unsigned short* h   = (unsigned short*)d_ws;     // NH bf16
    unsigned short* dbf = h + NH;                    // NH bf16
    unsigned short* abf = dbf + NH;                  // NH bf16
    float* wsum = (float*)(abf + NH);                // N
    int2* edge2 = (int2*)(wsum + N_NODES);           // E
    int2* bbuf  = edge2 + N_EDGES;                   // E
    int* off    = (int*)(bbuf + N_EDGES);            // N+1
    int* bcnt   = off + N_NODES + 1;                 // NB (zeroed)
    int* bcur   = bcnt + NB;                         // NB
    int* boff   = bcur + NB;                         // NB+1
    int* goff   = boff + NB + 1;                     // G+1

    hipMemsetAsync(bcnt, 0, NB * sizeof(int), stream);

    k_emb_hist<<<EMB_BLOCKS + HIST_BLOCKS, 256, 0, stream>>>(x, w_emb, b_emb, h, dst, bcnt);
    k_boff_bounds<<<1 + (N_NODES + 511) / 512, 512, 0, stream>>>(bcnt, boff, bcur, batch, goff);
    k_bucket<<<CBLK, 1024, 0, stream>>>(src, dst, eattr, bcur, bbuf);
    k_csr<<<NB, 256, 0, stream>>>(bbuf, boff, off, wsum, edge2);

    int gemm_blocks = (N_NODES + 63) / 64;
    int agg_blocks = (N_NODES + 3) / 4;

    for (int l = 0; l < 2; ++l) {
        const float* W1 = lin1_w + l * HDIM * HDIM;
        const float* B1 = lin1_b + l * HDIM;
        const float* W2 = lin2_w + l * HDIM * HDIM;
        const float* W3 = lin3_w + l * HDIM * HDIM;
        const float* B3 = lin3_b + l * HDIM;
        k_gemm3<<<gemm_blocks, 256, 0, stream>>>(h, W1, B1, W2, W3, B3, wsum, abf, dbf);
        k_agg<<<agg_blocks, 256, 0, stream>>>(edge2, off, abf, dbf, h);
    }

    k_poolhead<<<G_GRAPHS, 128, 0, stream>>>(h, goff, mlp_w1, mlp_b1, mlp_w2, mlp_b2, out);
}